// Round 4
// baseline (737.007 us; speedup 1.0000x reference)
//
#include <hip/hip_runtime.h>

// Problem constants: B=16,N=100,E=9900,M=50,F=64,H=128,K=20,D=2,T=8,S=8
#define BB 16
#define NN 100
#define EE 9900
#define MM 50
#define FF 64
#define HH 128
#define KK 20
#define DD 2
#define ROWS (BB*EE)      // 158400 edge rows
#define HROWS (BB*MM)     // 800 hyper rows
#define BN_CNT (BB*NN)    // 1600

#define EPSF 1e-5f

typedef __attribute__((ext_vector_type(8))) short bf16x8;
typedef __attribute__((ext_vector_type(4))) float f32x4;

__device__ __forceinline__ float lrelu(float x) { return (x >= 0.f) ? x : 0.01f * x; }

__device__ __forceinline__ unsigned short f2bf(float x) {
  unsigned u = __float_as_uint(x);
  return (unsigned short)((u + 0x7fffu + ((u >> 16) & 1u)) >> 16);
}
__device__ __forceinline__ unsigned pk2(float a, float b) {
  return (unsigned)f2bf(a) | ((unsigned)f2bf(b) << 16);
}
__device__ __forceinline__ float bf2f(unsigned short u) {
  return __uint_as_float(((unsigned)u) << 16);
}

// ---------------- Threefry-2x32 (bit-exact vs JAX) ----------------
__device__ __forceinline__ void tf2x32(unsigned k0, unsigned k1,
                                       unsigned x0, unsigned x1,
                                       unsigned& o0, unsigned& o1) {
  unsigned ks2 = k0 ^ k1 ^ 0x1BD11BDAu;
  x0 += k0; x1 += k1;
#define TFR(r) { x0 += x1; x1 = (x1 << r) | (x1 >> (32 - r)); x1 ^= x0; }
  TFR(13) TFR(15) TFR(26) TFR(6)   x0 += k1;  x1 += ks2 + 1u;
  TFR(17) TFR(29) TFR(16) TFR(24)  x0 += ks2; x1 += k0 + 2u;
  TFR(13) TFR(15) TFR(26) TFR(6)   x0 += k0;  x1 += k1 + 3u;
  TFR(17) TFR(29) TFR(16) TFR(24)  x0 += k1;  x1 += ks2 + 4u;
  TFR(13) TFR(15) TFR(26) TFR(6)   x0 += ks2; x1 += k0 + 5u;
#undef TFR
  o0 = x0; o1 = x1;
}

__device__ __forceinline__ float bits_to_normal(unsigned bits) {
  float f = __uint_as_float((bits >> 9) | 0x3f800000u) - 1.0f;  // [0,1)
  const float lo = -0.99999994f;                                 // nextafter(-1,0)
  float x = fmaxf(lo, fmaf(f, 2.0f, lo));
  float w = -log1pf(-x * x);
  float p;
  if (w < 5.0f) {
    w = w - 2.5f;
    p = 2.81022636e-08f;
    p = fmaf(p, w, 3.43273939e-07f);
    p = fmaf(p, w, -3.5233877e-06f);
    p = fmaf(p, w, -4.39150654e-06f);
    p = fmaf(p, w, 0.00021858087f);
    p = fmaf(p, w, -0.00125372503f);
    p = fmaf(p, w, -0.00417768164f);
    p = fmaf(p, w, 0.246640727f);
    p = fmaf(p, w, 1.50140941f);
  } else {
    w = sqrtf(w) - 3.0f;
    p = -0.000200214257f;
    p = fmaf(p, w, 0.000100950558f);
    p = fmaf(p, w, 0.00134934322f);
    p = fmaf(p, w, -0.00367342844f);
    p = fmaf(p, w, 0.00573950773f);
    p = fmaf(p, w, -0.0076224613f);
    p = fmaf(p, w, 0.00943887047f);
    p = fmaf(p, w, 1.00167406f);
    p = fmaf(p, w, 2.83297682f);
  }
  return 1.41421356237f * (p * x);
}

// ---------------- prep: W -> bf16 transposed [c][k] ----------------
__global__ __launch_bounds__(256) void k_prepw(const float* __restrict__ W1,
                                               const float* __restrict__ W2,
                                               unsigned short* __restrict__ WtG) {
  int t = blockIdx.x * 256 + threadIdx.x;     // 0..32767
  int w = t >> 14, rem = t & 16383;
  int c = rem & 127, k = rem >> 7;
  const float* W = w ? W2 : W1;
  WtG[w * 16384 + c * 128 + k] = f2bf(W[k * 128 + c]);
}

// ---------------- scales: mean over last dim (4) ----------------
__global__ void k_scales(const float* __restrict__ rtg, const float* __restrict__ rth,
                         float* __restrict__ sg, float* __restrict__ sh) {
  int i = blockIdx.x * blockDim.x + threadIdx.x;
  if (i < ROWS) {
    float4 r = ((const float4*)rtg)[i];
    sg[i] = (r.x + r.y + r.z + r.w) * 0.25f;
  }
  int j = i - ROWS;
  if (j >= 0 && j < HROWS) {
    float4 r = ((const float4*)rth)[j];
    sh[j] = (r.x + r.y + r.z + r.w) * 0.25f;
  }
}

// ---------------- edge MLP layer: bf16 MFMA GEMM + fused BN/lrelu + stats ------------
// Y[r][c] = sum_k X[r][k] W[k][c] + bias  via swapped MFMA: D[m=c][n=r] = A[c][k]*B[k][r]
//   A-frag (W^T): lane l reads WtL[(cb+l&15)][kk + (l>>4)*8 ..+7]  (contiguous)
//   B-frag (X):   lane l reads Xt[(rb+l&15)][kk + (l>>4)*8 ..+7]   (contiguous)
//   D: lane l holds rows r=rb+(l&15), cols c=cb+(l>>4)*4+reg
// MODE 0: X = [recv|send] gathered from v.  MODE 1: X = lrelu(bn(Yin)).
#define WPITCH 136
#define XPITCH 136
template <int MODE>
__global__ __launch_bounds__(256) void k_edge_gemm(
    const float* __restrict__ v, const unsigned short* __restrict__ WtG,
    const unsigned short* __restrict__ Yin, unsigned short* __restrict__ Yout,
    const float* __restrict__ bias,
    const float* __restrict__ gmm, const float* __restrict__ beta,
    const float* __restrict__ stats_in, float* __restrict__ stats_out) {
  __shared__ unsigned short WtL[128 * WPITCH];
  __shared__ unsigned short Xt[64 * XPITCH];
  __shared__ float aColP[132], bColP[132];
  const int tid = threadIdx.x;
  const int r0 = blockIdx.x * 64;

  if (MODE == 1 && tid < 128) {
    float s = stats_in[tid], ss = stats_in[128 + tid];
    float mu = s * (1.f / ROWS);
    float var = fmaxf(ss * (1.f / ROWS) - mu * mu, 0.f);
    float rs = 1.f / sqrtf(var + EPSF);
    float a = rs * gmm[tid];
    int pi = tid + (tid >> 5);                 // padded index (k + k/32), conflict-free
    aColP[pi] = a; bColP[pi] = beta[tid] - mu * a;
  }
  if (MODE == 1) __syncthreads();

  // stage W: pre-transposed bf16 [128][128] -> LDS [128][WPITCH]
#pragma unroll
  for (int it = 0; it < 8; ++it) {
    int idx = it * 256 + tid;                  // 16B chunk id
    int row = idx >> 4, cc = (idx & 15) * 8;
    *(uint4*)&WtL[row * WPITCH + cc] = *(const uint4*)&WtG[idx * 8];
  }

  // stage X tile (64 rows x 128 k) as bf16
  const int rsi = tid >> 2, q = tid & 3, k0 = q * 32;
  if (MODE == 0) {
    int g = r0 + rsi;
    int b = g / EE; int e = g - b * EE;
    int i = e / 99; int jj = e - i * 99; int j = jj + ((jj >= i) ? 1 : 0);
    int vsrc = (q < 2) ? ((b * NN + i) * FF + q * 32)
                       : ((b * NN + j) * FF + (q - 2) * 32);
#pragma unroll
    for (int i2 = 0; i2 < 4; ++i2) {
      float4 xa = *(const float4*)&v[vsrc + i2 * 8];
      float4 xb = *(const float4*)&v[vsrc + i2 * 8 + 4];
      uint4 pk;
      pk.x = pk2(xa.x, xa.y); pk.y = pk2(xa.z, xa.w);
      pk.z = pk2(xb.x, xb.y); pk.w = pk2(xb.z, xb.w);
      *(uint4*)&Xt[rsi * XPITCH + k0 + i2 * 8] = pk;
    }
  } else {
    const unsigned short* src = Yin + (size_t)(r0 + rsi) * 128 + k0;
#pragma unroll
    for (int i2 = 0; i2 < 4; ++i2) {
      uint4 raw = *(const uint4*)&src[i2 * 8];
      unsigned rr[4] = {raw.x, raw.y, raw.z, raw.w};
      unsigned ow[4];
#pragma unroll
      for (int u = 0; u < 4; ++u) {
        int k = k0 + i2 * 8 + u * 2;
        int p1 = k + (k >> 5);
        float xl = __uint_as_float(rr[u] << 16);
        float xh = __uint_as_float(rr[u] & 0xffff0000u);
        xl = lrelu(fmaf(xl, aColP[p1], bColP[p1]));
        xh = lrelu(fmaf(xh, aColP[p1 + 1], bColP[p1 + 1]));
        ow[u] = pk2(xl, xh);
      }
      uint4 pk; pk.x = ow[0]; pk.y = ow[1]; pk.z = ow[2]; pk.w = ow[3];
      *(uint4*)&Xt[rsi * XPITCH + k0 + i2 * 8] = pk;
    }
  }
  __syncthreads();

  // MFMA: each wave computes 64 rows x 32 cols (cb = wid*32)
  const int lane = tid & 63, wid = tid >> 6;
  const int l15 = lane & 15, lq = lane >> 4;
  const int cb = wid * 32;
  f32x4 acc[2][4];
#pragma unroll
  for (int a = 0; a < 2; ++a)
#pragma unroll
    for (int b2 = 0; b2 < 4; ++b2) acc[a][b2] = (f32x4){0.f, 0.f, 0.f, 0.f};

  const unsigned short* Ab0 = &WtL[(cb + l15) * WPITCH + lq * 8];
  const unsigned short* Ab1 = &WtL[(cb + 16 + l15) * WPITCH + lq * 8];
  const unsigned short* Bb = &Xt[l15 * XPITCH + lq * 8];
#pragma unroll
  for (int kc = 0; kc < 4; ++kc) {
    int ko = kc * 32;
    bf16x8 a0 = *(const bf16x8*)(Ab0 + ko);
    bf16x8 a1 = *(const bf16x8*)(Ab1 + ko);
#pragma unroll
    for (int rbi = 0; rbi < 4; ++rbi) {
      bf16x8 bfr = *(const bf16x8*)(Bb + rbi * 16 * XPITCH + ko);
      acc[0][rbi] = __builtin_amdgcn_mfma_f32_16x16x32_bf16(a0, bfr, acc[0][rbi], 0, 0, 0);
      acc[1][rbi] = __builtin_amdgcn_mfma_f32_16x16x32_bf16(a1, bfr, acc[1][rbi], 0, 0, 0);
    }
  }

  // epilogue: +bias, bf16 store, column stats (f32)
  float4 bi0 = *(const float4*)&bias[cb + lq * 4];
  float4 bi1 = *(const float4*)&bias[cb + 16 + lq * 4];
  f32x4 bv0 = {bi0.x, bi0.y, bi0.z, bi0.w};
  f32x4 bv1 = {bi1.x, bi1.y, bi1.z, bi1.w};
  f32x4 s0 = {0.f,0.f,0.f,0.f}, ss0 = {0.f,0.f,0.f,0.f};
  f32x4 s1 = {0.f,0.f,0.f,0.f}, ss1 = {0.f,0.f,0.f,0.f};
#pragma unroll
  for (int rbi = 0; rbi < 4; ++rbi) {
    size_t r = (size_t)(r0 + rbi * 16 + l15);
    f32x4 y0 = acc[0][rbi] + bv0;
    f32x4 y1 = acc[1][rbi] + bv1;
    uint2 w0; w0.x = pk2(y0.x, y0.y); w0.y = pk2(y0.z, y0.w);
    uint2 w1; w1.x = pk2(y1.x, y1.y); w1.y = pk2(y1.z, y1.w);
    *(uint2*)&Yout[r * 128 + cb + lq * 4] = w0;
    *(uint2*)&Yout[r * 128 + cb + 16 + lq * 4] = w1;
    s0 += y0; ss0 += y0 * y0;
    s1 += y1; ss1 += y1 * y1;
  }
#pragma unroll
  for (int off = 1; off <= 8; off <<= 1) {
#pragma unroll
    for (int c = 0; c < 4; ++c) {
      s0[c] += __shfl_xor(s0[c], off);
      ss0[c] += __shfl_xor(ss0[c], off);
      s1[c] += __shfl_xor(s1[c], off);
      ss1[c] += __shfl_xor(ss1[c], off);
    }
  }
  if (l15 == 0) {
    int c0 = cb + lq * 4;
#pragma unroll
    for (int u = 0; u < 4; ++u) {
      atomicAdd(&stats_out[c0 + u], s0[u]);
      atomicAdd(&stats_out[128 + c0 + u], ss0[u]);
      atomicAdd(&stats_out[c0 + 16 + u], s1[u]);
      atomicAdd(&stats_out[128 + c0 + 16 + u], ss1[u]);
    }
  }
}

// ---------------- receiver gather-reduce: hidden_g ----------------
__global__ __launch_bounds__(128) void k_recv(
    const unsigned short* __restrict__ Y, const float* __restrict__ stats2,
    const float* __restrict__ g2, const float* __restrict__ be2,
    const float* __restrict__ scaleg, const float* __restrict__ v,
    float* __restrict__ hg) {
  int bn = blockIdx.x; int b = bn / NN, n = bn - b * NN;
  int h = threadIdx.x;
  float s = stats2[h], ss = stats2[128 + h];
  float mu = s * (1.f / ROWS);
  float var = fmaxf(ss * (1.f / ROWS) - mu * mu, 0.f);
  float rs = 1.f / sqrtf(var + EPSF);
  float a = rs * g2[h]; float bc = be2[h] - mu * a;
  float sv = (h >= 64) ? v[(b * NN + n) * FF + (h - 64)] : 0.f;
  float acc = 0.f;
#pragma unroll 4
  for (int i = 0; i < NN; ++i) {
    if (i == n) continue;
    int e = i * 99 + ((n < i) ? n : n - 1);
    int row = b * EE + e;
    float y = bf2f(Y[(size_t)row * 128 + h]);
    float msgv = lrelu(y * a + bc);
    float pre = (h < 64) ? v[(b * NN + i) * FF + h] : sv;
    float ag = lrelu(fmaf(msgv, scaleg[row], pre));
    acc += ag;
  }
  hg[bn * 128 + h] = acc * 0.5f;  // / D
}

// ---------------- hyper path ----------------
__global__ __launch_bounds__(128) void k_h1(const float* __restrict__ I_HG,
                                            const float* __restrict__ v,
                                            const float* __restrict__ W1h,
                                            const float* __restrict__ b1h,
                                            float* __restrict__ y1h) {
  int bm = blockIdx.x; int b = bm / MM, m = bm - b * MM;
  __shared__ float prerow[FF];
  int t = threadIdx.x;
  if (t < FF) {
    float s = 0.f;
    for (int n = 0; n < NN; ++n)
      s = fmaf(I_HG[(b * NN + n) * MM + m], v[(b * NN + n) * FF + t], s);
    prerow[t] = s;
  }
  __syncthreads();
  float y = b1h[t];
  for (int f = 0; f < FF; ++f) y = fmaf(prerow[f], W1h[f * 128 + t], y);
  y1h[bm * 128 + t] = y;
}

__global__ __launch_bounds__(64) void k_colstats(const float* __restrict__ X, int R,
                                                 float* __restrict__ stats) {
  int c = blockIdx.x;
  int t = threadIdx.x;
  float s = 0.f, ss = 0.f;
  for (int r = t; r < R; r += 64) {
    float x = X[(size_t)r * 128 + c];
    s += x; ss += x * x;
  }
  for (int off = 32; off; off >>= 1) {
    s += __shfl_down(s, off, 64);
    ss += __shfl_down(ss, off, 64);
  }
  if (t == 0) { stats[c] = s; stats[128 + c] = ss; }
}

__global__ __launch_bounds__(128) void k_h2(const float* __restrict__ y1h,
                                            const float* __restrict__ statsh1,
                                            const float* __restrict__ g1h,
                                            const float* __restrict__ be1h,
                                            const float* __restrict__ W2h,
                                            const float* __restrict__ b2h,
                                            float* __restrict__ y2h) {
  int bm = blockIdx.x; int t = threadIdx.x;
  __shared__ float trow[128];
  float s = statsh1[t], ss = statsh1[128 + t];
  float mu = s * (1.f / HROWS);
  float var = fmaxf(ss * (1.f / HROWS) - mu * mu, 0.f);
  float rs = 1.f / sqrtf(var + EPSF);
  float a = rs * g1h[t]; float bc = be1h[t] - mu * a;
  trow[t] = lrelu(y1h[bm * 128 + t] * a + bc);
  __syncthreads();
  float y = b2h[t];
  for (int f = 0; f < 128; ++f) y = fmaf(trow[f], W2h[f * 128 + t], y);
  y2h[bm * 128 + t] = y;
}

__global__ __launch_bounds__(128) void k_h3(const float* __restrict__ y2h,
                                            const float* __restrict__ statsh2,
                                            const float* __restrict__ g2h,
                                            const float* __restrict__ be2h,
                                            const float* __restrict__ scaleh,
                                            const float* __restrict__ I_HG,
                                            float* __restrict__ hh) {
  int bn = blockIdx.x; int b = bn / NN, n = bn - b * NN;
  int h = threadIdx.x;
  float s = statsh2[h], ss = statsh2[128 + h];
  float mu = s * (1.f / HROWS);
  float var = fmaxf(ss * (1.f / HROWS) - mu * mu, 0.f);
  float rs = 1.f / sqrtf(var + EPSF);
  float a = rs * g2h[h]; float bc = be2h[h] - mu * a;
  float acc = 0.f;
  for (int m = 0; m < MM; ++m) {
    float x = lrelu(y2h[(b * MM + m) * 128 + h] * a + bc);
    acc = fmaf(x * scaleh[b * MM + m], I_HG[(b * NN + n) * MM + m], acc);
  }
  hh[bn * 128 + h] = acc * 0.5f;  // / D
}

// ---------------- v layer + heads ----------------
__global__ __launch_bounds__(128) void k_ve(
    const float* __restrict__ hg, const float* __restrict__ hh,
    const float* __restrict__ Wo1, const float* __restrict__ bo1,
    const float* __restrict__ Wa, const float* __restrict__ ba,
    const float* __restrict__ Wm, const float* __restrict__ bm,
    float* __restrict__ valpha, float* __restrict__ vmu, float* __restrict__ vcore) {
  __shared__ __align__(16) float cat[8][256];
  __shared__ float vres[8][128];
  __shared__ float lgs[KK], mrow[KK * DD], alsh[KK];
  int r0 = blockIdx.x * 8;
  int t = threadIdx.x;
  for (int q = t; q < 2048; q += 128) {
    int rr = q >> 8, k = q & 255;
    cat[rr][k] = (k < 128) ? hg[(r0 + rr) * 128 + k] : hh[(r0 + rr) * 128 + (k - 128)];
  }
  __syncthreads();
  float acc[8] = {0, 0, 0, 0, 0, 0, 0, 0};
  for (int k = 0; k < 256; ++k) {
    float wv = Wo1[k * 128 + t];
#pragma unroll
    for (int q = 0; q < 8; ++q) acc[q] = fmaf(cat[q][k], wv, acc[q]);
  }
  float bb = bo1[t];
#pragma unroll
  for (int q = 0; q < 8; ++q) vres[q][t] = lrelu(acc[q] + bb);
  __syncthreads();
  for (int q = 0; q < 8; ++q) {
    int row = r0 + q;
    if (t < KK) {
      float s = ba[t];
      for (int f = 0; f < 128; ++f) s = fmaf(vres[q][f], Wa[f * KK + t], s);
      lgs[t] = s;
    } else if (t >= 64 && t < 64 + KK * DD) {
      int c = t - 64;
      float s = bm[c];
      for (int f = 0; f < 128; ++f) s = fmaf(vres[q][f], Wm[f * (KK * DD) + c], s);
      mrow[c] = s;
      vmu[row * (KK * DD) + c] = s;
    }
    __syncthreads();
    if (t < KK) {
      float mx = lgs[0];
      for (int k2 = 1; k2 < KK; ++k2) mx = fmaxf(mx, lgs[k2]);
      float se = 0.f;
      for (int k2 = 0; k2 < KK; ++k2) se += expf(lgs[k2] - mx);
      float al = expf(lgs[t] - mx) / se;
      alsh[t] = al;
      valpha[row * KK + t] = al;
    }
    __syncthreads();
    if (t < DD) {
      float s = 0.f;
      for (int k2 = 0; k2 < KK; ++k2) s = fmaf(alsh[k2], mrow[k2 * DD + t], s);
      vcore[row * DD + t] = s;
    }
    __syncthreads();
  }
}

// ---------------- decoder outputs (exact JAX threefry noise, partitionable XOR) -------
__global__ __launch_bounds__(64) void k_out(const float* __restrict__ data,
                                            const float* __restrict__ valpha,
                                            const float* __restrict__ vmu,
                                            const float* __restrict__ vcore,
                                            float* __restrict__ out) {
  int bn = blockIdx.x; int t = threadIdx.x;
  __shared__ float nz[8][2];
  __shared__ float insarr[8][2];
  __shared__ float alsh[KK];
  if (t < 16) {
    int s = t >> 1, d = t & 1;
    unsigned fk0, fk1;
    tf2x32(0u, 1234u, 0u, (unsigned)s, fk0, fk1);        // fold_in(key(1234), s)
    unsigned flat = (unsigned)(bn * 2 + d);
    unsigned o0, o1;
    tf2x32(fk0, fk1, 0u, flat, o0, o1);                   // counter-mode
    nz[s][d] = bits_to_normal(o0 ^ o1);                   // XOR both lanes
  }
  if (t < KK) alsh[t] = valpha[bn * KK + t];
  __syncthreads();
  if (t < 2) {
    int d = t;
    float ins0 = data[bn * 16 + d];
    float core = vcore[bn * 2 + d];
    float p = ins0;
    for (int s = 0; s < 8; ++s) {
      insarr[s][d] = p;
      p = (p + core) + nz[s][d];
      out[(bn * 8 + s) * 2 + d] = p;
    }
  }
  __syncthreads();
  for (int q = t; q < 160; q += 64) {
    int k = q % KK;
    out[25600 + bn * 160 + q] = alsh[k];
  }
  for (int q = t; q < 320; q += 64) {
    int s = q / 40, kd = q - s * 40, d = kd & 1;
    out[281600 + bn * 320 + q] = vmu[bn * 40 + kd] + insarr[s][d];
  }
  for (int q = t; q < 320; q += 64) out[793600 + bn * 320 + q] = 1.0f;
}

extern "C" void kernel_launch(void* const* d_in, const int* in_sizes, int n_in,
                              void* d_out, int out_size, void* d_ws, size_t ws_size,
                              hipStream_t stream) {
  const float* data  = (const float*)d_in[0];
  const float* rtg   = (const float*)d_in[3];
  const float* rth   = (const float*)d_in[4];
  const float* I_HG  = (const float*)d_in[5];
  const float* v     = (const float*)d_in[6];
  const float* W1g   = (const float*)d_in[7];
  const float* b1g   = (const float*)d_in[8];
  const float* g1g   = (const float*)d_in[9];
  const float* be1g  = (const float*)d_in[10];
  const float* W2g   = (const float*)d_in[11];
  const float* b2g   = (const float*)d_in[12];
  const float* g2g   = (const float*)d_in[13];
  const float* be2g  = (const float*)d_in[14];
  const float* W1h   = (const float*)d_in[15];
  const float* b1h   = (const float*)d_in[16];
  const float* g1h   = (const float*)d_in[17];
  const float* be1h  = (const float*)d_in[18];
  const float* W2h   = (const float*)d_in[19];
  const float* b2h   = (const float*)d_in[20];
  const float* g2h   = (const float*)d_in[21];
  const float* be2h  = (const float*)d_in[22];
  const float* Wo1   = (const float*)d_in[23];
  const float* bo1   = (const float*)d_in[24];
  const float* Wa    = (const float*)d_in[25];
  const float* ba    = (const float*)d_in[26];
  const float* Wm    = (const float*)d_in[27];
  const float* bm    = (const float*)d_in[28];
  char* wsb  = (char*)d_ws;
  float* out = (float*)d_out;

  // byte-offset workspace layout
  unsigned short* Ybf = (unsigned short*)wsb;                        // 40,550,400 B
  float* stats1  = (float*)(wsb + 40550400);                         // 256
  float* stats2  = stats1 + 256;
  float* statsh1 = stats2 + 256;
  float* statsh2 = statsh1 + 256;
  float* scaleg  = (float*)(wsb + 40550400 + 4096);                  // ROWS
  float* scaleh  = scaleg + ROWS;                                     // HROWS
  float* hg      = scaleh + HROWS;                                    // 1600*128
  float* hh      = hg + BN_CNT * 128;
  float* y1h     = hh + BN_CNT * 128;                                 // 800*128
  float* y2h     = y1h + HROWS * 128;
  float* va      = y2h + HROWS * 128;                                 // 1600*20
  float* vmu     = va + BN_CNT * KK;                                  // 1600*40
  float* vcore   = vmu + BN_CNT * KK * DD;                            // 1600*2
  unsigned short* WtG = (unsigned short*)(vcore + BN_CNT * DD);       // 2*16384

  hipMemsetAsync(stats1, 0, 4096, stream);
  k_prepw<<<128, 256, 0, stream>>>(W1g, W2g, WtG);
  k_scales<<<(ROWS + HROWS + 255) / 256, 256, 0, stream>>>(rtg, rth, scaleg, scaleh);
  k_edge_gemm<0><<<ROWS / 64, 256, 0, stream>>>(v, WtG, nullptr, Ybf, b1g,
                                                nullptr, nullptr, nullptr, stats1);
  k_edge_gemm<1><<<ROWS / 64, 256, 0, stream>>>(v, WtG + 16384, Ybf, Ybf, b2g,
                                                g1g, be1g, stats1, stats2);
  k_recv<<<BN_CNT, 128, 0, stream>>>(Ybf, stats2, g2g, be2g, scaleg, v, hg);
  k_h1<<<HROWS, 128, 0, stream>>>(I_HG, v, W1h, b1h, y1h);
  k_colstats<<<128, 64, 0, stream>>>(y1h, HROWS, statsh1);
  k_h2<<<HROWS, 128, 0, stream>>>(y1h, statsh1, g1h, be1h, W2h, b2h, y2h);
  k_colstats<<<128, 64, 0, stream>>>(y2h, HROWS, statsh2);
  k_h3<<<BN_CNT, 128, 0, stream>>>(y2h, statsh2, g2h, be2h, scaleh, I_HG, hh);
  k_ve<<<BN_CNT / 8, 128, 0, stream>>>(hg, hh, Wo1, bo1, Wa, ba, Wm, bm, va, vmu, vcore);
  k_out<<<BN_CNT, 64, 0, stream>>>(data, va, vmu, vcore, out);
}

// Round 5
// 435.457 us; speedup vs baseline: 1.6925x; 1.6925x over previous
//
#include <hip/hip_runtime.h>

// Problem constants: B=16,N=100,E=9900,M=50,F=64,H=128,K=20,D=2,T=8,S=8
#define BB 16
#define NN 100
#define EE 9900
#define MM 50
#define FF 64
#define HH 128
#define KK 20
#define DD 2
#define ROWS (BB*EE)      // 158400 edge rows
#define HROWS (BB*MM)     // 800 hyper rows
#define BN_CNT (BB*NN)    // 1600

#define EPSF 1e-5f

typedef __attribute__((ext_vector_type(8))) short bf16x8;
typedef __attribute__((ext_vector_type(4))) float f32x4;

__device__ __forceinline__ float lrelu(float x) { return (x >= 0.f) ? x : 0.01f * x; }

__device__ __forceinline__ unsigned short f2bf(float x) {
  unsigned u = __float_as_uint(x);
  return (unsigned short)((u + 0x7fffu + ((u >> 16) & 1u)) >> 16);
}
__device__ __forceinline__ unsigned pk2(float a, float b) {
  return (unsigned)f2bf(a) | ((unsigned)f2bf(b) << 16);
}
__device__ __forceinline__ float bf2f(unsigned short u) {
  return __uint_as_float(((unsigned)u) << 16);
}

// ---------------- Threefry-2x32 (bit-exact vs JAX) ----------------
__device__ __forceinline__ void tf2x32(unsigned k0, unsigned k1,
                                       unsigned x0, unsigned x1,
                                       unsigned& o0, unsigned& o1) {
  unsigned ks2 = k0 ^ k1 ^ 0x1BD11BDAu;
  x0 += k0; x1 += k1;
#define TFR(r) { x0 += x1; x1 = (x1 << r) | (x1 >> (32 - r)); x1 ^= x0; }
  TFR(13) TFR(15) TFR(26) TFR(6)   x0 += k1;  x1 += ks2 + 1u;
  TFR(17) TFR(29) TFR(16) TFR(24)  x0 += ks2; x1 += k0 + 2u;
  TFR(13) TFR(15) TFR(26) TFR(6)   x0 += k0;  x1 += k1 + 3u;
  TFR(17) TFR(29) TFR(16) TFR(24)  x0 += k1;  x1 += ks2 + 4u;
  TFR(13) TFR(15) TFR(26) TFR(6)   x0 += ks2; x1 += k0 + 5u;
#undef TFR
  o0 = x0; o1 = x1;
}

__device__ __forceinline__ float bits_to_normal(unsigned bits) {
  float f = __uint_as_float((bits >> 9) | 0x3f800000u) - 1.0f;  // [0,1)
  const float lo = -0.99999994f;                                 // nextafter(-1,0)
  float x = fmaxf(lo, fmaf(f, 2.0f, lo));
  float w = -log1pf(-x * x);
  float p;
  if (w < 5.0f) {
    w = w - 2.5f;
    p = 2.81022636e-08f;
    p = fmaf(p, w, 3.43273939e-07f);
    p = fmaf(p, w, -3.5233877e-06f);
    p = fmaf(p, w, -4.39150654e-06f);
    p = fmaf(p, w, 0.00021858087f);
    p = fmaf(p, w, -0.00125372503f);
    p = fmaf(p, w, -0.00417768164f);
    p = fmaf(p, w, 0.246640727f);
    p = fmaf(p, w, 1.50140941f);
  } else {
    w = sqrtf(w) - 3.0f;
    p = -0.000200214257f;
    p = fmaf(p, w, 0.000100950558f);
    p = fmaf(p, w, 0.00134934322f);
    p = fmaf(p, w, -0.00367342844f);
    p = fmaf(p, w, 0.00573950773f);
    p = fmaf(p, w, -0.0076224613f);
    p = fmaf(p, w, 0.00943887047f);
    p = fmaf(p, w, 1.00167406f);
    p = fmaf(p, w, 2.83297682f);
  }
  return 1.41421356237f * (p * x);
}

// ---------------- prep: W -> bf16 transposed [c][k] ----------------
__global__ __launch_bounds__(256) void k_prepw(const float* __restrict__ W1,
                                               const float* __restrict__ W2,
                                               unsigned short* __restrict__ WtG) {
  int t = blockIdx.x * 256 + threadIdx.x;     // 0..32767
  int w = t >> 14, rem = t & 16383;
  int c = rem & 127, k = rem >> 7;
  const float* W = w ? W2 : W1;
  WtG[w * 16384 + c * 128 + k] = f2bf(W[k * 128 + c]);
}

// ---------------- scales: mean over last dim (4) ----------------
__global__ void k_scales(const float* __restrict__ rtg, const float* __restrict__ rth,
                         float* __restrict__ sg, float* __restrict__ sh) {
  int i = blockIdx.x * blockDim.x + threadIdx.x;
  if (i < ROWS) {
    float4 r = ((const float4*)rtg)[i];
    sg[i] = (r.x + r.y + r.z + r.w) * 0.25f;
  }
  int j = i - ROWS;
  if (j >= 0 && j < HROWS) {
    float4 r = ((const float4*)rth)[j];
    sh[j] = (r.x + r.y + r.z + r.w) * 0.25f;
  }
}

// ---------------- edge MLP layer: bf16 MFMA GEMM + fused BN/lrelu + stats ------------
// Y[r][c] = sum_k X[r][k] W[k][c] + bias  via swapped MFMA: D[m=c][n=r] = A[c][k]*B[k][r]
//   A-frag (W^T): lane l holds W^T rows cb+(l&15), cb+16+(l&15) in REGISTERS (L2-hot W)
//   B-frag (X):   lane l reads Xt[(rb+l&15)][kk + (l>>4)*8 ..+7]   (contiguous LDS)
//   D: lane l holds rows r=rb+(l&15), cols c=cb+(l>>4)*4+reg
// MODE 0: X = [recv|send] gathered from v.  MODE 1: X = lrelu(bn(Yin)).
// Stats epilogue: LDS ds_add reduce -> 2 dense 64-lane global atomics per 128 threads
// (sparse per-lane global atomics were the R4 249us stall — 158K atomic instrs).
#define XPITCH 136
template <int MODE>
__global__ __launch_bounds__(256) void k_edge_gemm(
    const float* __restrict__ v, const unsigned short* __restrict__ WtG,
    const unsigned short* __restrict__ Yin, unsigned short* __restrict__ Yout,
    const float* __restrict__ bias,
    const float* __restrict__ gmm, const float* __restrict__ beta,
    const float* __restrict__ stats_in, float* __restrict__ stats_out) {
  __shared__ unsigned short Xt[64 * XPITCH];
  __shared__ float aColP[132], bColP[132];
  __shared__ float bsum[128], bssq[128];
  const int tid = threadIdx.x;
  const int r0 = blockIdx.x * 64;
  const int lane = tid & 63, wid = tid >> 6;
  const int l15 = lane & 15, lq = lane >> 4;
  const int cb = wid * 32;

  if (tid < 128) {
    bsum[tid] = 0.f; bssq[tid] = 0.f;
    if (MODE == 1) {
      float s = stats_in[tid], ss = stats_in[128 + tid];
      float mu = s * (1.f / ROWS);
      float var = fmaxf(ss * (1.f / ROWS) - mu * mu, 0.f);
      float rs = 1.f / sqrtf(var + EPSF);
      float a = rs * gmm[tid];
      int pi = tid + (tid >> 5);                 // padded index, conflict-free
      aColP[pi] = a; bColP[pi] = beta[tid] - mu * a;
    }
  }

  // W fragments: global -> registers (32KB WtG is L2-resident, shared by all blocks)
  const unsigned short* WA = WtG + (cb + l15) * 128 + lq * 8;
  bf16x8 a0[4], a1[4];
#pragma unroll
  for (int kc = 0; kc < 4; ++kc) {
    a0[kc] = *(const bf16x8*)(WA + kc * 32);
    a1[kc] = *(const bf16x8*)(WA + 16 * 128 + kc * 32);
  }

  if (MODE == 1) __syncthreads();   // aColP/bColP visible before staging uses them

  // stage X tile (64 rows x 128 k) as bf16
  const int rsi = tid >> 2, q = tid & 3, k0 = q * 32;
  if (MODE == 0) {
    int g = r0 + rsi;
    int b = g / EE; int e = g - b * EE;
    int i = e / 99; int jj = e - i * 99; int j = jj + ((jj >= i) ? 1 : 0);
    int vsrc = (q < 2) ? ((b * NN + i) * FF + q * 32)
                       : ((b * NN + j) * FF + (q - 2) * 32);
#pragma unroll
    for (int i2 = 0; i2 < 4; ++i2) {
      float4 xa = *(const float4*)&v[vsrc + i2 * 8];
      float4 xb = *(const float4*)&v[vsrc + i2 * 8 + 4];
      uint4 pk;
      pk.x = pk2(xa.x, xa.y); pk.y = pk2(xa.z, xa.w);
      pk.z = pk2(xb.x, xb.y); pk.w = pk2(xb.z, xb.w);
      *(uint4*)&Xt[rsi * XPITCH + k0 + i2 * 8] = pk;
    }
  } else {
    const unsigned short* src = Yin + (size_t)(r0 + rsi) * 128 + k0;
#pragma unroll
    for (int i2 = 0; i2 < 4; ++i2) {
      uint4 raw = *(const uint4*)&src[i2 * 8];
      unsigned rr[4] = {raw.x, raw.y, raw.z, raw.w};
      unsigned ow[4];
#pragma unroll
      for (int u = 0; u < 4; ++u) {
        int k = k0 + i2 * 8 + u * 2;
        int p1 = k + (k >> 5);
        float xl = __uint_as_float(rr[u] << 16);
        float xh = __uint_as_float(rr[u] & 0xffff0000u);
        xl = lrelu(fmaf(xl, aColP[p1], bColP[p1]));
        xh = lrelu(fmaf(xh, aColP[p1 + 1], bColP[p1 + 1]));
        ow[u] = pk2(xl, xh);
      }
      uint4 pk; pk.x = ow[0]; pk.y = ow[1]; pk.z = ow[2]; pk.w = ow[3];
      *(uint4*)&Xt[rsi * XPITCH + k0 + i2 * 8] = pk;
    }
  }
  __syncthreads();

  // MFMA: each wave computes 64 rows x 32 cols (cb = wid*32)
  f32x4 acc[2][4];
#pragma unroll
  for (int a = 0; a < 2; ++a)
#pragma unroll
    for (int b2 = 0; b2 < 4; ++b2) acc[a][b2] = (f32x4){0.f, 0.f, 0.f, 0.f};

  const unsigned short* Bb = &Xt[l15 * XPITCH + lq * 8];
#pragma unroll
  for (int kc = 0; kc < 4; ++kc) {
    int ko = kc * 32;
#pragma unroll
    for (int rbi = 0; rbi < 4; ++rbi) {
      bf16x8 bfr = *(const bf16x8*)(Bb + rbi * 16 * XPITCH + ko);
      acc[0][rbi] = __builtin_amdgcn_mfma_f32_16x16x32_bf16(a0[kc], bfr, acc[0][rbi], 0, 0, 0);
      acc[1][rbi] = __builtin_amdgcn_mfma_f32_16x16x32_bf16(a1[kc], bfr, acc[1][rbi], 0, 0, 0);
    }
  }

  // epilogue: +bias, bf16 store, column stats
  float4 bi0 = *(const float4*)&bias[cb + lq * 4];
  float4 bi1 = *(const float4*)&bias[cb + 16 + lq * 4];
  f32x4 bv0 = {bi0.x, bi0.y, bi0.z, bi0.w};
  f32x4 bv1 = {bi1.x, bi1.y, bi1.z, bi1.w};
  f32x4 s0 = {0.f,0.f,0.f,0.f}, ss0 = {0.f,0.f,0.f,0.f};
  f32x4 s1 = {0.f,0.f,0.f,0.f}, ss1 = {0.f,0.f,0.f,0.f};
#pragma unroll
  for (int rbi = 0; rbi < 4; ++rbi) {
    size_t r = (size_t)(r0 + rbi * 16 + l15);
    f32x4 y0 = acc[0][rbi] + bv0;
    f32x4 y1 = acc[1][rbi] + bv1;
    uint2 w0; w0.x = pk2(y0.x, y0.y); w0.y = pk2(y0.z, y0.w);
    uint2 w1; w1.x = pk2(y1.x, y1.y); w1.y = pk2(y1.z, y1.w);
    *(uint2*)&Yout[r * 128 + cb + lq * 4] = w0;
    *(uint2*)&Yout[r * 128 + cb + 16 + lq * 4] = w1;
    s0 += y0; ss0 += y0 * y0;
    s1 += y1; ss1 += y1 * y1;
  }
  // LDS reduce (ds_add_f32, bank-parallel), then dense global atomics
#pragma unroll
  for (int u = 0; u < 4; ++u) {
    atomicAdd(&bsum[cb + lq * 4 + u], s0[u]);
    atomicAdd(&bssq[cb + lq * 4 + u], ss0[u]);
    atomicAdd(&bsum[cb + 16 + lq * 4 + u], s1[u]);
    atomicAdd(&bssq[cb + 16 + lq * 4 + u], ss1[u]);
  }
  __syncthreads();
  if (tid < 128) {
    atomicAdd(&stats_out[tid], bsum[tid]);
    atomicAdd(&stats_out[128 + tid], bssq[tid]);
  }
}

// ---------------- receiver gather-reduce: hidden_g ----------------
__global__ __launch_bounds__(128) void k_recv(
    const unsigned short* __restrict__ Y, const float* __restrict__ stats2,
    const float* __restrict__ g2, const float* __restrict__ be2,
    const float* __restrict__ scaleg, const float* __restrict__ v,
    float* __restrict__ hg) {
  int bn = blockIdx.x; int b = bn / NN, n = bn - b * NN;
  int h = threadIdx.x;
  float s = stats2[h], ss = stats2[128 + h];
  float mu = s * (1.f / ROWS);
  float var = fmaxf(ss * (1.f / ROWS) - mu * mu, 0.f);
  float rs = 1.f / sqrtf(var + EPSF);
  float a = rs * g2[h]; float bc = be2[h] - mu * a;
  float sv = (h >= 64) ? v[(b * NN + n) * FF + (h - 64)] : 0.f;
  float acc = 0.f;
#pragma unroll 4
  for (int i = 0; i < NN; ++i) {
    if (i == n) continue;
    int e = i * 99 + ((n < i) ? n : n - 1);
    int row = b * EE + e;
    float y = bf2f(Y[(size_t)row * 128 + h]);
    float msgv = lrelu(y * a + bc);
    float pre = (h < 64) ? v[(b * NN + i) * FF + h] : sv;
    float ag = lrelu(fmaf(msgv, scaleg[row], pre));
    acc += ag;
  }
  hg[bn * 128 + h] = acc * 0.5f;  // / D
}

// ---------------- hyper path ----------------
__global__ __launch_bounds__(128) void k_h1(const float* __restrict__ I_HG,
                                            const float* __restrict__ v,
                                            const float* __restrict__ W1h,
                                            const float* __restrict__ b1h,
                                            float* __restrict__ y1h) {
  int bm = blockIdx.x; int b = bm / MM, m = bm - b * MM;
  __shared__ float prerow[FF];
  int t = threadIdx.x;
  if (t < FF) {
    float s = 0.f;
    for (int n = 0; n < NN; ++n)
      s = fmaf(I_HG[(b * NN + n) * MM + m], v[(b * NN + n) * FF + t], s);
    prerow[t] = s;
  }
  __syncthreads();
  float y = b1h[t];
  for (int f = 0; f < FF; ++f) y = fmaf(prerow[f], W1h[f * 128 + t], y);
  y1h[bm * 128 + t] = y;
}

__global__ __launch_bounds__(64) void k_colstats(const float* __restrict__ X, int R,
                                                 float* __restrict__ stats) {
  int c = blockIdx.x;
  int t = threadIdx.x;
  float s = 0.f, ss = 0.f;
  for (int r = t; r < R; r += 64) {
    float x = X[(size_t)r * 128 + c];
    s += x; ss += x * x;
  }
  for (int off = 32; off; off >>= 1) {
    s += __shfl_down(s, off, 64);
    ss += __shfl_down(ss, off, 64);
  }
  if (t == 0) { stats[c] = s; stats[128 + c] = ss; }
}

__global__ __launch_bounds__(128) void k_h2(const float* __restrict__ y1h,
                                            const float* __restrict__ statsh1,
                                            const float* __restrict__ g1h,
                                            const float* __restrict__ be1h,
                                            const float* __restrict__ W2h,
                                            const float* __restrict__ b2h,
                                            float* __restrict__ y2h) {
  int bm = blockIdx.x; int t = threadIdx.x;
  __shared__ float trow[128];
  float s = statsh1[t], ss = statsh1[128 + t];
  float mu = s * (1.f / HROWS);
  float var = fmaxf(ss * (1.f / HROWS) - mu * mu, 0.f);
  float rs = 1.f / sqrtf(var + EPSF);
  float a = rs * g1h[t]; float bc = be1h[t] - mu * a;
  trow[t] = lrelu(y1h[bm * 128 + t] * a + bc);
  __syncthreads();
  float y = b2h[t];
  for (int f = 0; f < 128; ++f) y = fmaf(trow[f], W2h[f * 128 + t], y);
  y2h[bm * 128 + t] = y;
}

__global__ __launch_bounds__(128) void k_h3(const float* __restrict__ y2h,
                                            const float* __restrict__ statsh2,
                                            const float* __restrict__ g2h,
                                            const float* __restrict__ be2h,
                                            const float* __restrict__ scaleh,
                                            const float* __restrict__ I_HG,
                                            float* __restrict__ hh) {
  int bn = blockIdx.x; int b = bn / NN, n = bn - b * NN;
  int h = threadIdx.x;
  float s = statsh2[h], ss = statsh2[128 + h];
  float mu = s * (1.f / HROWS);
  float var = fmaxf(ss * (1.f / HROWS) - mu * mu, 0.f);
  float rs = 1.f / sqrtf(var + EPSF);
  float a = rs * g2h[h]; float bc = be2h[h] - mu * a;
  float acc = 0.f;
  for (int m = 0; m < MM; ++m) {
    float x = lrelu(y2h[(b * MM + m) * 128 + h] * a + bc);
    acc = fmaf(x * scaleh[b * MM + m], I_HG[(b * NN + n) * MM + m], acc);
  }
  hh[bn * 128 + h] = acc * 0.5f;  // / D
}

// ---------------- v layer + heads ----------------
__global__ __launch_bounds__(128) void k_ve(
    const float* __restrict__ hg, const float* __restrict__ hh,
    const float* __restrict__ Wo1, const float* __restrict__ bo1,
    const float* __restrict__ Wa, const float* __restrict__ ba,
    const float* __restrict__ Wm, const float* __restrict__ bm,
    float* __restrict__ valpha, float* __restrict__ vmu, float* __restrict__ vcore) {
  __shared__ __align__(16) float cat[8][256];
  __shared__ float vres[8][128];
  __shared__ float lgs[KK], mrow[KK * DD], alsh[KK];
  int r0 = blockIdx.x * 8;
  int t = threadIdx.x;
  for (int q = t; q < 2048; q += 128) {
    int rr = q >> 8, k = q & 255;
    cat[rr][k] = (k < 128) ? hg[(r0 + rr) * 128 + k] : hh[(r0 + rr) * 128 + (k - 128)];
  }
  __syncthreads();
  float acc[8] = {0, 0, 0, 0, 0, 0, 0, 0};
  for (int k = 0; k < 256; ++k) {
    float wv = Wo1[k * 128 + t];
#pragma unroll
    for (int q = 0; q < 8; ++q) acc[q] = fmaf(cat[q][k], wv, acc[q]);
  }
  float bb = bo1[t];
#pragma unroll
  for (int q = 0; q < 8; ++q) vres[q][t] = lrelu(acc[q] + bb);
  __syncthreads();
  for (int q = 0; q < 8; ++q) {
    int row = r0 + q;
    if (t < KK) {
      float s = ba[t];
      for (int f = 0; f < 128; ++f) s = fmaf(vres[q][f], Wa[f * KK + t], s);
      lgs[t] = s;
    } else if (t >= 64 && t < 64 + KK * DD) {
      int c = t - 64;
      float s = bm[c];
      for (int f = 0; f < 128; ++f) s = fmaf(vres[q][f], Wm[f * (KK * DD) + c], s);
      mrow[c] = s;
      vmu[row * (KK * DD) + c] = s;
    }
    __syncthreads();
    if (t < KK) {
      float mx = lgs[0];
      for (int k2 = 1; k2 < KK; ++k2) mx = fmaxf(mx, lgs[k2]);
      float se = 0.f;
      for (int k2 = 0; k2 < KK; ++k2) se += expf(lgs[k2] - mx);
      float al = expf(lgs[t] - mx) / se;
      alsh[t] = al;
      valpha[row * KK + t] = al;
    }
    __syncthreads();
    if (t < DD) {
      float s = 0.f;
      for (int k2 = 0; k2 < KK; ++k2) s = fmaf(alsh[k2], mrow[k2 * DD + t], s);
      vcore[row * DD + t] = s;
    }
    __syncthreads();
  }
}

// ---------------- decoder outputs (exact JAX threefry noise, partitionable XOR) -------
__global__ __launch_bounds__(64) void k_out(const float* __restrict__ data,
                                            const float* __restrict__ valpha,
                                            const float* __restrict__ vmu,
                                            const float* __restrict__ vcore,
                                            float* __restrict__ out) {
  int bn = blockIdx.x; int t = threadIdx.x;
  __shared__ float nz[8][2];
  __shared__ float insarr[8][2];
  __shared__ float alsh[KK];
  if (t < 16) {
    int s = t >> 1, d = t & 1;
    unsigned fk0, fk1;
    tf2x32(0u, 1234u, 0u, (unsigned)s, fk0, fk1);        // fold_in(key(1234), s)
    unsigned flat = (unsigned)(bn * 2 + d);
    unsigned o0, o1;
    tf2x32(fk0, fk1, 0u, flat, o0, o1);                   // counter-mode
    nz[s][d] = bits_to_normal(o0 ^ o1);                   // XOR both lanes
  }
  if (t < KK) alsh[t] = valpha[bn * KK + t];
  __syncthreads();
  if (t < 2) {
    int d = t;
    float ins0 = data[bn * 16 + d];
    float core = vcore[bn * 2 + d];
    float p = ins0;
    for (int s = 0; s < 8; ++s) {
      insarr[s][d] = p;
      p = (p + core) + nz[s][d];
      out[(bn * 8 + s) * 2 + d] = p;
    }
  }
  __syncthreads();
  for (int q = t; q < 160; q += 64) {
    int k = q % KK;
    out[25600 + bn * 160 + q] = alsh[k];
  }
  for (int q = t; q < 320; q += 64) {
    int s = q / 40, kd = q - s * 40, d = kd & 1;
    out[281600 + bn * 320 + q] = vmu[bn * 40 + kd] + insarr[s][d];
  }
  for (int q = t; q < 320; q += 64) out[793600 + bn * 320 + q] = 1.0f;
}

extern "C" void kernel_launch(void* const* d_in, const int* in_sizes, int n_in,
                              void* d_out, int out_size, void* d_ws, size_t ws_size,
                              hipStream_t stream) {
  const float* data  = (const float*)d_in[0];
  const float* rtg   = (const float*)d_in[3];
  const float* rth   = (const float*)d_in[4];
  const float* I_HG  = (const float*)d_in[5];
  const float* v     = (const float*)d_in[6];
  const float* W1g   = (const float*)d_in[7];
  const float* b1g   = (const float*)d_in[8];
  const float* g1g   = (const float*)d_in[9];
  const float* be1g  = (const float*)d_in[10];
  const float* W2g   = (const float*)d_in[11];
  const float* b2g   = (const float*)d_in[12];
  const float* g2g   = (const float*)d_in[13];
  const float* be2g  = (const float*)d_in[14];
  const float* W1h   = (const float*)d_in[15];
  const float* b1h   = (const float*)d_in[16];
  const float* g1h   = (const float*)d_in[17];
  const float* be1h  = (const float*)d_in[18];
  const float* W2h   = (const float*)d_in[19];
  const float* b2h   = (const float*)d_in[20];
  const float* g2h   = (const float*)d_in[21];
  const float* be2h  = (const float*)d_in[22];
  const float* Wo1   = (const float*)d_in[23];
  const float* bo1   = (const float*)d_in[24];
  const float* Wa    = (const float*)d_in[25];
  const float* ba    = (const float*)d_in[26];
  const float* Wm    = (const float*)d_in[27];
  const float* bm    = (const float*)d_in[28];
  char* wsb  = (char*)d_ws;
  float* out = (float*)d_out;

  // byte-offset workspace layout
  unsigned short* Ybf = (unsigned short*)wsb;                        // 40,550,400 B
  float* stats1  = (float*)(wsb + 40550400);                         // 256
  float* stats2  = stats1 + 256;
  float* statsh1 = stats2 + 256;
  float* statsh2 = statsh1 + 256;
  float* scaleg  = (float*)(wsb + 40550400 + 4096);                  // ROWS
  float* scaleh  = scaleg + ROWS;                                     // HROWS
  float* hg      = scaleh + HROWS;                                    // 1600*128
  float* hh      = hg + BN_CNT * 128;
  float* y1h     = hh + BN_CNT * 128;                                 // 800*128
  float* y2h     = y1h + HROWS * 128;
  float* va      = y2h + HROWS * 128;                                 // 1600*20
  float* vmu     = va + BN_CNT * KK;                                  // 1600*40
  float* vcore   = vmu + BN_CNT * KK * DD;                            // 1600*2
  unsigned short* WtG = (unsigned short*)(vcore + BN_CNT * DD);       // 2*16384

  hipMemsetAsync(stats1, 0, 4096, stream);
  k_prepw<<<128, 256, 0, stream>>>(W1g, W2g, WtG);
  k_scales<<<(ROWS + HROWS + 255) / 256, 256, 0, stream>>>(rtg, rth, scaleg, scaleh);
  k_edge_gemm<0><<<ROWS / 64, 256, 0, stream>>>(v, WtG, nullptr, Ybf, b1g,
                                                nullptr, nullptr, nullptr, stats1);
  k_edge_gemm<1><<<ROWS / 64, 256, 0, stream>>>(v, WtG + 16384, Ybf, Ybf, b2g,
                                                g1g, be1g, stats1, stats2);
  k_recv<<<BN_CNT, 128, 0, stream>>>(Ybf, stats2, g2g, be2g, scaleg, v, hg);
  k_h1<<<HROWS, 128, 0, stream>>>(I_HG, v, W1h, b1h, y1h);
  k_colstats<<<128, 64, 0, stream>>>(y1h, HROWS, statsh1);
  k_h2<<<HROWS, 128, 0, stream>>>(y1h, statsh1, g1h, be1h, W2h, b2h, y2h);
  k_colstats<<<128, 64, 0, stream>>>(y2h, HROWS, statsh2);
  k_h3<<<BN_CNT, 128, 0, stream>>>(y2h, statsh2, g2h, be2h, scaleh, I_HG, hh);
  k_ve<<<BN_CNT / 8, 128, 0, stream>>>(hg, hh, Wo1, bo1, Wa, ba, Wm, bm, va, vmu, vcore);
  k_out<<<BN_CNT, 64, 0, stream>>>(data, va, vmu, vcore, out);
}

// Round 6
// 433.143 us; speedup vs baseline: 1.7015x; 1.0053x over previous
//
#include <hip/hip_runtime.h>

// Problem constants: B=16,N=100,E=9900,M=50,F=64,H=128,K=20,D=2,T=8,S=8
#define BB 16
#define NN 100
#define EE 9900
#define MM 50
#define FF 64
#define HH 128
#define KK 20
#define DD 2
#define ROWS (BB*EE)      // 158400 edge rows
#define HROWS (BB*MM)     // 800 hyper rows
#define BN_CNT (BB*NN)    // 1600
#define NBLK (ROWS/64)    // 2475 gemm blocks
#define RED1 99           // stage-1 reduce blocks
#define RED1_ROWS (NBLK/RED1)  // 25

#define EPSF 1e-5f

typedef __attribute__((ext_vector_type(8))) short bf16x8;
typedef __attribute__((ext_vector_type(4))) float f32x4;

__device__ __forceinline__ float lrelu(float x) { return (x >= 0.f) ? x : 0.01f * x; }

__device__ __forceinline__ unsigned short f2bf(float x) {
  unsigned u = __float_as_uint(x);
  return (unsigned short)((u + 0x7fffu + ((u >> 16) & 1u)) >> 16);
}
__device__ __forceinline__ unsigned pk2(float a, float b) {
  return (unsigned)f2bf(a) | ((unsigned)f2bf(b) << 16);
}
__device__ __forceinline__ float bf2f(unsigned short u) {
  return __uint_as_float(((unsigned)u) << 16);
}

// ---------------- Threefry-2x32 (bit-exact vs JAX) ----------------
__device__ __forceinline__ void tf2x32(unsigned k0, unsigned k1,
                                       unsigned x0, unsigned x1,
                                       unsigned& o0, unsigned& o1) {
  unsigned ks2 = k0 ^ k1 ^ 0x1BD11BDAu;
  x0 += k0; x1 += k1;
#define TFR(r) { x0 += x1; x1 = (x1 << r) | (x1 >> (32 - r)); x1 ^= x0; }
  TFR(13) TFR(15) TFR(26) TFR(6)   x0 += k1;  x1 += ks2 + 1u;
  TFR(17) TFR(29) TFR(16) TFR(24)  x0 += ks2; x1 += k0 + 2u;
  TFR(13) TFR(15) TFR(26) TFR(6)   x0 += k0;  x1 += k1 + 3u;
  TFR(17) TFR(29) TFR(16) TFR(24)  x0 += k1;  x1 += ks2 + 4u;
  TFR(13) TFR(15) TFR(26) TFR(6)   x0 += ks2; x1 += k0 + 5u;
#undef TFR
  o0 = x0; o1 = x1;
}

__device__ __forceinline__ float bits_to_normal(unsigned bits) {
  float f = __uint_as_float((bits >> 9) | 0x3f800000u) - 1.0f;  // [0,1)
  const float lo = -0.99999994f;                                 // nextafter(-1,0)
  float x = fmaxf(lo, fmaf(f, 2.0f, lo));
  float w = -log1pf(-x * x);
  float p;
  if (w < 5.0f) {
    w = w - 2.5f;
    p = 2.81022636e-08f;
    p = fmaf(p, w, 3.43273939e-07f);
    p = fmaf(p, w, -3.5233877e-06f);
    p = fmaf(p, w, -4.39150654e-06f);
    p = fmaf(p, w, 0.00021858087f);
    p = fmaf(p, w, -0.00125372503f);
    p = fmaf(p, w, -0.00417768164f);
    p = fmaf(p, w, 0.246640727f);
    p = fmaf(p, w, 1.50140941f);
  } else {
    w = sqrtf(w) - 3.0f;
    p = -0.000200214257f;
    p = fmaf(p, w, 0.000100950558f);
    p = fmaf(p, w, 0.00134934322f);
    p = fmaf(p, w, -0.00367342844f);
    p = fmaf(p, w, 0.00573950773f);
    p = fmaf(p, w, -0.0076224613f);
    p = fmaf(p, w, 0.00943887047f);
    p = fmaf(p, w, 1.00167406f);
    p = fmaf(p, w, 2.83297682f);
  }
  return 1.41421356237f * (p * x);
}

// ---------------- prep: W -> bf16 transposed [c][k] ----------------
__global__ __launch_bounds__(256) void k_prepw(const float* __restrict__ W1,
                                               const float* __restrict__ W2,
                                               unsigned short* __restrict__ WtG) {
  int t = blockIdx.x * 256 + threadIdx.x;     // 0..32767
  int w = t >> 14, rem = t & 16383;
  int c = rem & 127, k = rem >> 7;
  const float* W = w ? W2 : W1;
  WtG[w * 16384 + c * 128 + k] = f2bf(W[k * 128 + c]);
}

// ---------------- scales: mean over last dim (4) ----------------
__global__ void k_scales(const float* __restrict__ rtg, const float* __restrict__ rth,
                         float* __restrict__ sg, float* __restrict__ sh) {
  int i = blockIdx.x * blockDim.x + threadIdx.x;
  if (i < ROWS) {
    float4 r = ((const float4*)rtg)[i];
    sg[i] = (r.x + r.y + r.z + r.w) * 0.25f;
  }
  int j = i - ROWS;
  if (j >= 0 && j < HROWS) {
    float4 r = ((const float4*)rth)[j];
    sh[j] = (r.x + r.y + r.z + r.w) * 0.25f;
  }
}

// ---------------- stats tree reduction (replaces the 100us same-address atomics) -----
__global__ __launch_bounds__(256) void k_red1(const float* __restrict__ partials,
                                              float* __restrict__ partial2) {
  int j = blockIdx.x, t = threadIdx.x;
  const float* p = partials + (size_t)j * RED1_ROWS * 256 + t;
  float s = 0.f;
#pragma unroll 5
  for (int r = 0; r < RED1_ROWS; ++r) s += p[(size_t)r * 256];
  partial2[j * 256 + t] = s;
}
__global__ __launch_bounds__(256) void k_red2(const float* __restrict__ partial2,
                                              float* __restrict__ stats) {
  int t = threadIdx.x;
  float s = 0.f;
#pragma unroll 9
  for (int r = 0; r < RED1; ++r) s += partial2[r * 256 + t];
  stats[t] = s;
}

// ---------------- edge MLP layer: bf16 MFMA GEMM + fused BN/lrelu + partial stats ----
// Y[r][c] = sum_k X[r][k] W[k][c] + bias  via swapped MFMA: D[m=c][n=r] = A[c][k]*B[k][r]
// Stats: LDS reduce -> per-block contiguous store to partials[block][256] (NO atomics).
#define XPITCH 136
template <int MODE>
__global__ __launch_bounds__(256) void k_edge_gemm(
    const float* __restrict__ v, const unsigned short* __restrict__ WtG,
    const unsigned short* __restrict__ Yin, unsigned short* __restrict__ Yout,
    const float* __restrict__ bias,
    const float* __restrict__ gmm, const float* __restrict__ beta,
    const float* __restrict__ stats_in, float* __restrict__ partials) {
  __shared__ unsigned short Xt[64 * XPITCH];
  __shared__ float aColP[132], bColP[132];
  __shared__ float bsum[128], bssq[128];
  const int tid = threadIdx.x;
  const int r0 = blockIdx.x * 64;
  const int lane = tid & 63, wid = tid >> 6;
  const int l15 = lane & 15, lq = lane >> 4;
  const int cb = wid * 32;

  if (tid < 128) {
    bsum[tid] = 0.f; bssq[tid] = 0.f;
    if (MODE == 1) {
      float s = stats_in[tid], ss = stats_in[128 + tid];
      float mu = s * (1.f / ROWS);
      float var = fmaxf(ss * (1.f / ROWS) - mu * mu, 0.f);
      float rs = 1.f / sqrtf(var + EPSF);
      float a = rs * gmm[tid];
      int pi = tid + (tid >> 5);                 // padded index, conflict-free
      aColP[pi] = a; bColP[pi] = beta[tid] - mu * a;
    }
  }

  // W fragments: global -> registers (32KB WtG is L2-resident, shared by all blocks)
  const unsigned short* WA = WtG + (cb + l15) * 128 + lq * 8;
  bf16x8 a0[4], a1[4];
#pragma unroll
  for (int kc = 0; kc < 4; ++kc) {
    a0[kc] = *(const bf16x8*)(WA + kc * 32);
    a1[kc] = *(const bf16x8*)(WA + 16 * 128 + kc * 32);
  }

  if (MODE == 1) __syncthreads();   // aColP/bColP visible before staging uses them

  // stage X tile (64 rows x 128 k) as bf16
  const int rsi = tid >> 2, q = tid & 3, k0 = q * 32;
  if (MODE == 0) {
    int g = r0 + rsi;
    int b = g / EE; int e = g - b * EE;
    int i = e / 99; int jj = e - i * 99; int j = jj + ((jj >= i) ? 1 : 0);
    int vsrc = (q < 2) ? ((b * NN + i) * FF + q * 32)
                       : ((b * NN + j) * FF + (q - 2) * 32);
#pragma unroll
    for (int i2 = 0; i2 < 4; ++i2) {
      float4 xa = *(const float4*)&v[vsrc + i2 * 8];
      float4 xb = *(const float4*)&v[vsrc + i2 * 8 + 4];
      uint4 pk;
      pk.x = pk2(xa.x, xa.y); pk.y = pk2(xa.z, xa.w);
      pk.z = pk2(xb.x, xb.y); pk.w = pk2(xb.z, xb.w);
      *(uint4*)&Xt[rsi * XPITCH + k0 + i2 * 8] = pk;
    }
  } else {
    const unsigned short* src = Yin + (size_t)(r0 + rsi) * 128 + k0;
#pragma unroll
    for (int i2 = 0; i2 < 4; ++i2) {
      uint4 raw = *(const uint4*)&src[i2 * 8];
      unsigned rr[4] = {raw.x, raw.y, raw.z, raw.w};
      unsigned ow[4];
#pragma unroll
      for (int u = 0; u < 4; ++u) {
        int k = k0 + i2 * 8 + u * 2;
        int p1 = k + (k >> 5);
        float xl = __uint_as_float(rr[u] << 16);
        float xh = __uint_as_float(rr[u] & 0xffff0000u);
        xl = lrelu(fmaf(xl, aColP[p1], bColP[p1]));
        xh = lrelu(fmaf(xh, aColP[p1 + 1], bColP[p1 + 1]));
        ow[u] = pk2(xl, xh);
      }
      uint4 pk; pk.x = ow[0]; pk.y = ow[1]; pk.z = ow[2]; pk.w = ow[3];
      *(uint4*)&Xt[rsi * XPITCH + k0 + i2 * 8] = pk;
    }
  }
  __syncthreads();

  // MFMA: each wave computes 64 rows x 32 cols (cb = wid*32)
  f32x4 acc[2][4];
#pragma unroll
  for (int a = 0; a < 2; ++a)
#pragma unroll
    for (int b2 = 0; b2 < 4; ++b2) acc[a][b2] = (f32x4){0.f, 0.f, 0.f, 0.f};

  const unsigned short* Bb = &Xt[l15 * XPITCH + lq * 8];
#pragma unroll
  for (int kc = 0; kc < 4; ++kc) {
    int ko = kc * 32;
#pragma unroll
    for (int rbi = 0; rbi < 4; ++rbi) {
      bf16x8 bfr = *(const bf16x8*)(Bb + rbi * 16 * XPITCH + ko);
      acc[0][rbi] = __builtin_amdgcn_mfma_f32_16x16x32_bf16(a0[kc], bfr, acc[0][rbi], 0, 0, 0);
      acc[1][rbi] = __builtin_amdgcn_mfma_f32_16x16x32_bf16(a1[kc], bfr, acc[1][rbi], 0, 0, 0);
    }
  }

  // epilogue: +bias, bf16 store, column stats
  float4 bi0 = *(const float4*)&bias[cb + lq * 4];
  float4 bi1 = *(const float4*)&bias[cb + 16 + lq * 4];
  f32x4 bv0 = {bi0.x, bi0.y, bi0.z, bi0.w};
  f32x4 bv1 = {bi1.x, bi1.y, bi1.z, bi1.w};
  f32x4 s0 = {0.f,0.f,0.f,0.f}, ss0 = {0.f,0.f,0.f,0.f};
  f32x4 s1 = {0.f,0.f,0.f,0.f}, ss1 = {0.f,0.f,0.f,0.f};
#pragma unroll
  for (int rbi = 0; rbi < 4; ++rbi) {
    size_t r = (size_t)(r0 + rbi * 16 + l15);
    f32x4 y0 = acc[0][rbi] + bv0;
    f32x4 y1 = acc[1][rbi] + bv1;
    uint2 w0; w0.x = pk2(y0.x, y0.y); w0.y = pk2(y0.z, y0.w);
    uint2 w1; w1.x = pk2(y1.x, y1.y); w1.y = pk2(y1.z, y1.w);
    *(uint2*)&Yout[r * 128 + cb + lq * 4] = w0;
    *(uint2*)&Yout[r * 128 + cb + 16 + lq * 4] = w1;
    s0 += y0; ss0 += y0 * y0;
    s1 += y1; ss1 += y1 * y1;
  }
  // LDS reduce (ds_add_f32, bank-parallel), then contiguous per-block partial store
#pragma unroll
  for (int u = 0; u < 4; ++u) {
    atomicAdd(&bsum[cb + lq * 4 + u], s0[u]);
    atomicAdd(&bssq[cb + lq * 4 + u], ss0[u]);
    atomicAdd(&bsum[cb + 16 + lq * 4 + u], s1[u]);
    atomicAdd(&bssq[cb + 16 + lq * 4 + u], ss1[u]);
  }
  __syncthreads();
  if (tid < 128) {
    partials[(size_t)blockIdx.x * 256 + tid] = bsum[tid];
    partials[(size_t)blockIdx.x * 256 + 128 + tid] = bssq[tid];
  }
}

// ---------------- receiver gather-reduce: hidden_g ----------------
__global__ __launch_bounds__(128) void k_recv(
    const unsigned short* __restrict__ Y, const float* __restrict__ stats2,
    const float* __restrict__ g2, const float* __restrict__ be2,
    const float* __restrict__ scaleg, const float* __restrict__ v,
    float* __restrict__ hg) {
  int bn = blockIdx.x; int b = bn / NN, n = bn - b * NN;
  int h = threadIdx.x;
  float s = stats2[h], ss = stats2[128 + h];
  float mu = s * (1.f / ROWS);
  float var = fmaxf(ss * (1.f / ROWS) - mu * mu, 0.f);
  float rs = 1.f / sqrtf(var + EPSF);
  float a = rs * g2[h]; float bc = be2[h] - mu * a;
  float sv = (h >= 64) ? v[(b * NN + n) * FF + (h - 64)] : 0.f;
  float acc = 0.f;
#pragma unroll 4
  for (int i = 0; i < NN; ++i) {
    if (i == n) continue;
    int e = i * 99 + ((n < i) ? n : n - 1);
    int row = b * EE + e;
    float y = bf2f(Y[(size_t)row * 128 + h]);
    float msgv = lrelu(y * a + bc);
    float pre = (h < 64) ? v[(b * NN + i) * FF + h] : sv;
    float ag = lrelu(fmaf(msgv, scaleg[row], pre));
    acc += ag;
  }
  hg[bn * 128 + h] = acc * 0.5f;  // / D
}

// ---------------- hyper path ----------------
__global__ __launch_bounds__(128) void k_h1(const float* __restrict__ I_HG,
                                            const float* __restrict__ v,
                                            const float* __restrict__ W1h,
                                            const float* __restrict__ b1h,
                                            float* __restrict__ y1h) {
  int bm = blockIdx.x; int b = bm / MM, m = bm - b * MM;
  __shared__ float prerow[FF];
  int t = threadIdx.x;
  if (t < FF) {
    float s = 0.f;
    for (int n = 0; n < NN; ++n)
      s = fmaf(I_HG[(b * NN + n) * MM + m], v[(b * NN + n) * FF + t], s);
    prerow[t] = s;
  }
  __syncthreads();
  float y = b1h[t];
  for (int f = 0; f < FF; ++f) y = fmaf(prerow[f], W1h[f * 128 + t], y);
  y1h[bm * 128 + t] = y;
}

__global__ __launch_bounds__(64) void k_colstats(const float* __restrict__ X, int R,
                                                 float* __restrict__ stats) {
  int c = blockIdx.x;
  int t = threadIdx.x;
  float s = 0.f, ss = 0.f;
  for (int r = t; r < R; r += 64) {
    float x = X[(size_t)r * 128 + c];
    s += x; ss += x * x;
  }
  for (int off = 32; off; off >>= 1) {
    s += __shfl_down(s, off, 64);
    ss += __shfl_down(ss, off, 64);
  }
  if (t == 0) { stats[c] = s; stats[128 + c] = ss; }
}

__global__ __launch_bounds__(128) void k_h2(const float* __restrict__ y1h,
                                            const float* __restrict__ statsh1,
                                            const float* __restrict__ g1h,
                                            const float* __restrict__ be1h,
                                            const float* __restrict__ W2h,
                                            const float* __restrict__ b2h,
                                            float* __restrict__ y2h) {
  int bm = blockIdx.x; int t = threadIdx.x;
  __shared__ float trow[128];
  float s = statsh1[t], ss = statsh1[128 + t];
  float mu = s * (1.f / HROWS);
  float var = fmaxf(ss * (1.f / HROWS) - mu * mu, 0.f);
  float rs = 1.f / sqrtf(var + EPSF);
  float a = rs * g1h[t]; float bc = be1h[t] - mu * a;
  trow[t] = lrelu(y1h[bm * 128 + t] * a + bc);
  __syncthreads();
  float y = b2h[t];
  for (int f = 0; f < 128; ++f) y = fmaf(trow[f], W2h[f * 128 + t], y);
  y2h[bm * 128 + t] = y;
}

__global__ __launch_bounds__(128) void k_h3(const float* __restrict__ y2h,
                                            const float* __restrict__ statsh2,
                                            const float* __restrict__ g2h,
                                            const float* __restrict__ be2h,
                                            const float* __restrict__ scaleh,
                                            const float* __restrict__ I_HG,
                                            float* __restrict__ hh) {
  int bn = blockIdx.x; int b = bn / NN, n = bn - b * NN;
  int h = threadIdx.x;
  float s = statsh2[h], ss = statsh2[128 + h];
  float mu = s * (1.f / HROWS);
  float var = fmaxf(ss * (1.f / HROWS) - mu * mu, 0.f);
  float rs = 1.f / sqrtf(var + EPSF);
  float a = rs * g2h[h]; float bc = be2h[h] - mu * a;
  float acc = 0.f;
  for (int m = 0; m < MM; ++m) {
    float x = lrelu(y2h[(b * MM + m) * 128 + h] * a + bc);
    acc = fmaf(x * scaleh[b * MM + m], I_HG[(b * NN + n) * MM + m], acc);
  }
  hh[bn * 128 + h] = acc * 0.5f;  // / D
}

// ---------------- v layer + heads ----------------
__global__ __launch_bounds__(128) void k_ve(
    const float* __restrict__ hg, const float* __restrict__ hh,
    const float* __restrict__ Wo1, const float* __restrict__ bo1,
    const float* __restrict__ Wa, const float* __restrict__ ba,
    const float* __restrict__ Wm, const float* __restrict__ bm,
    float* __restrict__ valpha, float* __restrict__ vmu, float* __restrict__ vcore) {
  __shared__ __align__(16) float cat[8][256];
  __shared__ float vres[8][128];
  __shared__ float lgs[KK], mrow[KK * DD], alsh[KK];
  int r0 = blockIdx.x * 8;
  int t = threadIdx.x;
  for (int q = t; q < 2048; q += 128) {
    int rr = q >> 8, k = q & 255;
    cat[rr][k] = (k < 128) ? hg[(r0 + rr) * 128 + k] : hh[(r0 + rr) * 128 + (k - 128)];
  }
  __syncthreads();
  float acc[8] = {0, 0, 0, 0, 0, 0, 0, 0};
  for (int k = 0; k < 256; ++k) {
    float wv = Wo1[k * 128 + t];
#pragma unroll
    for (int q = 0; q < 8; ++q) acc[q] = fmaf(cat[q][k], wv, acc[q]);
  }
  float bb = bo1[t];
#pragma unroll
  for (int q = 0; q < 8; ++q) vres[q][t] = lrelu(acc[q] + bb);
  __syncthreads();
  for (int q = 0; q < 8; ++q) {
    int row = r0 + q;
    if (t < KK) {
      float s = ba[t];
      for (int f = 0; f < 128; ++f) s = fmaf(vres[q][f], Wa[f * KK + t], s);
      lgs[t] = s;
    } else if (t >= 64 && t < 64 + KK * DD) {
      int c = t - 64;
      float s = bm[c];
      for (int f = 0; f < 128; ++f) s = fmaf(vres[q][f], Wm[f * (KK * DD) + c], s);
      mrow[c] = s;
      vmu[row * (KK * DD) + c] = s;
    }
    __syncthreads();
    if (t < KK) {
      float mx = lgs[0];
      for (int k2 = 1; k2 < KK; ++k2) mx = fmaxf(mx, lgs[k2]);
      float se = 0.f;
      for (int k2 = 0; k2 < KK; ++k2) se += expf(lgs[k2] - mx);
      float al = expf(lgs[t] - mx) / se;
      alsh[t] = al;
      valpha[row * KK + t] = al;
    }
    __syncthreads();
    if (t < DD) {
      float s = 0.f;
      for (int k2 = 0; k2 < KK; ++k2) s = fmaf(alsh[k2], mrow[k2 * DD + t], s);
      vcore[row * DD + t] = s;
    }
    __syncthreads();
  }
}

// ---------------- decoder outputs (exact JAX threefry noise, partitionable XOR) -------
__global__ __launch_bounds__(64) void k_out(const float* __restrict__ data,
                                            const float* __restrict__ valpha,
                                            const float* __restrict__ vmu,
                                            const float* __restrict__ vcore,
                                            float* __restrict__ out) {
  int bn = blockIdx.x; int t = threadIdx.x;
  __shared__ float nz[8][2];
  __shared__ float insarr[8][2];
  __shared__ float alsh[KK];
  if (t < 16) {
    int s = t >> 1, d = t & 1;
    unsigned fk0, fk1;
    tf2x32(0u, 1234u, 0u, (unsigned)s, fk0, fk1);        // fold_in(key(1234), s)
    unsigned flat = (unsigned)(bn * 2 + d);
    unsigned o0, o1;
    tf2x32(fk0, fk1, 0u, flat, o0, o1);                   // counter-mode
    nz[s][d] = bits_to_normal(o0 ^ o1);                   // XOR both lanes
  }
  if (t < KK) alsh[t] = valpha[bn * KK + t];
  __syncthreads();
  if (t < 2) {
    int d = t;
    float ins0 = data[bn * 16 + d];
    float core = vcore[bn * 2 + d];
    float p = ins0;
    for (int s = 0; s < 8; ++s) {
      insarr[s][d] = p;
      p = (p + core) + nz[s][d];
      out[(bn * 8 + s) * 2 + d] = p;
    }
  }
  __syncthreads();
  for (int q = t; q < 160; q += 64) {
    int k = q % KK;
    out[25600 + bn * 160 + q] = alsh[k];
  }
  for (int q = t; q < 320; q += 64) {
    int s = q / 40, kd = q - s * 40, d = kd & 1;
    out[281600 + bn * 320 + q] = vmu[bn * 40 + kd] + insarr[s][d];
  }
  for (int q = t; q < 320; q += 64) out[793600 + bn * 320 + q] = 1.0f;
}

extern "C" void kernel_launch(void* const* d_in, const int* in_sizes, int n_in,
                              void* d_out, int out_size, void* d_ws, size_t ws_size,
                              hipStream_t stream) {
  const float* data  = (const float*)d_in[0];
  const float* rtg   = (const float*)d_in[3];
  const float* rth   = (const float*)d_in[4];
  const float* I_HG  = (const float*)d_in[5];
  const float* v     = (const float*)d_in[6];
  const float* W1g   = (const float*)d_in[7];
  const float* b1g   = (const float*)d_in[8];
  const float* g1g   = (const float*)d_in[9];
  const float* be1g  = (const float*)d_in[10];
  const float* W2g   = (const float*)d_in[11];
  const float* b2g   = (const float*)d_in[12];
  const float* g2g   = (const float*)d_in[13];
  const float* be2g  = (const float*)d_in[14];
  const float* W1h   = (const float*)d_in[15];
  const float* b1h   = (const float*)d_in[16];
  const float* g1h   = (const float*)d_in[17];
  const float* be1h  = (const float*)d_in[18];
  const float* W2h   = (const float*)d_in[19];
  const float* b2h   = (const float*)d_in[20];
  const float* g2h   = (const float*)d_in[21];
  const float* be2h  = (const float*)d_in[22];
  const float* Wo1   = (const float*)d_in[23];
  const float* bo1   = (const float*)d_in[24];
  const float* Wa    = (const float*)d_in[25];
  const float* ba    = (const float*)d_in[26];
  const float* Wm    = (const float*)d_in[27];
  const float* bm    = (const float*)d_in[28];
  char* wsb  = (char*)d_ws;
  float* out = (float*)d_out;

  // byte-offset workspace layout
  unsigned short* Ybf = (unsigned short*)wsb;                        // 40,550,400 B
  float* stats1  = (float*)(wsb + 40550400);                         // 256
  float* stats2  = stats1 + 256;
  float* statsh1 = stats2 + 256;
  float* statsh2 = statsh1 + 256;
  float* scaleg  = (float*)(wsb + 40550400 + 4096);                  // ROWS
  float* scaleh  = scaleg + ROWS;                                     // HROWS
  float* hg      = scaleh + HROWS;                                    // 1600*128
  float* hh      = hg + BN_CNT * 128;
  float* y1h     = hh + BN_CNT * 128;                                 // 800*128
  float* y2h     = y1h + HROWS * 128;
  float* va      = y2h + HROWS * 128;                                 // 1600*20
  float* vmu     = va + BN_CNT * KK;                                  // 1600*40
  float* vcore   = vmu + BN_CNT * KK * DD;                            // 1600*2
  unsigned short* WtG = (unsigned short*)(vcore + BN_CNT * DD);       // 2*16384 bf16
  float* partials = (float*)(WtG + 2 * 16384);                        // 2475*256 f32
  float* partial2 = partials + (size_t)NBLK * 256;                    // 99*256 f32

  k_prepw<<<128, 256, 0, stream>>>(W1g, W2g, WtG);
  k_scales<<<(ROWS + HROWS + 255) / 256, 256, 0, stream>>>(rtg, rth, scaleg, scaleh);
  k_edge_gemm<0><<<NBLK, 256, 0, stream>>>(v, WtG, nullptr, Ybf, b1g,
                                           nullptr, nullptr, nullptr, partials);
  k_red1<<<RED1, 256, 0, stream>>>(partials, partial2);
  k_red2<<<1, 256, 0, stream>>>(partial2, stats1);
  k_edge_gemm<1><<<NBLK, 256, 0, stream>>>(v, WtG + 16384, Ybf, Ybf, b2g,
                                           g1g, be1g, stats1, partials);
  k_red1<<<RED1, 256, 0, stream>>>(partials, partial2);
  k_red2<<<1, 256, 0, stream>>>(partial2, stats2);
  k_recv<<<BN_CNT, 128, 0, stream>>>(Ybf, stats2, g2g, be2g, scaleg, v, hg);
  k_h1<<<HROWS, 128, 0, stream>>>(I_HG, v, W1h, b1h, y1h);
  k_colstats<<<128, 64, 0, stream>>>(y1h, HROWS, statsh1);
  k_h2<<<HROWS, 128, 0, stream>>>(y1h, statsh1, g1h, be1h, W2h, b2h, y2h);
  k_colstats<<<128, 64, 0, stream>>>(y2h, HROWS, statsh2);
  k_h3<<<BN_CNT, 128, 0, stream>>>(y2h, statsh2, g2h, be2h, scaleh, I_HG, hh);
  k_ve<<<BN_CNT / 8, 128, 0, stream>>>(hg, hh, Wo1, bo1, Wa, ba, Wm, bm, va, vmu, vcore);
  k_out<<<BN_CNT, 64, 0, stream>>>(data, va, vmu, vcore, out);
}

// Round 7
// 378.442 us; speedup vs baseline: 1.9475x; 1.1445x over previous
//
#include <hip/hip_runtime.h>

// Problem constants: B=16,N=100,E=9900,M=50,F=64,H=128,K=20,D=2,T=8,S=8
#define BB 16
#define NN 100
#define EE 9900
#define MM 50
#define FF 64
#define HH 128
#define KK 20
#define DD 2
#define ROWS (BB*EE)      // 158400 edge rows
#define HROWS (BB*MM)     // 800 hyper rows
#define BN_CNT (BB*NN)    // 1600
#define NTILE (ROWS/64)   // 2475 tiles of 64 rows
#define TPB 5             // tiles per block (pipelined)
#define NBLK2 (NTILE/TPB) // 495 gemm blocks

#define EPSF 1e-5f

typedef __attribute__((ext_vector_type(8))) short bf16x8;
typedef __attribute__((ext_vector_type(4))) float f32x4;

__device__ __forceinline__ float lrelu(float x) { return (x >= 0.f) ? x : 0.01f * x; }

__device__ __forceinline__ unsigned short f2bf(float x) {
  unsigned u = __float_as_uint(x);
  return (unsigned short)((u + 0x7fffu + ((u >> 16) & 1u)) >> 16);
}
__device__ __forceinline__ unsigned pk2(float a, float b) {
  return (unsigned)f2bf(a) | ((unsigned)f2bf(b) << 16);
}
__device__ __forceinline__ float bf2f(unsigned short u) {
  return __uint_as_float(((unsigned)u) << 16);
}

// ---------------- Threefry-2x32 (bit-exact vs JAX) ----------------
__device__ __forceinline__ void tf2x32(unsigned k0, unsigned k1,
                                       unsigned x0, unsigned x1,
                                       unsigned& o0, unsigned& o1) {
  unsigned ks2 = k0 ^ k1 ^ 0x1BD11BDAu;
  x0 += k0; x1 += k1;
#define TFR(r) { x0 += x1; x1 = (x1 << r) | (x1 >> (32 - r)); x1 ^= x0; }
  TFR(13) TFR(15) TFR(26) TFR(6)   x0 += k1;  x1 += ks2 + 1u;
  TFR(17) TFR(29) TFR(16) TFR(24)  x0 += ks2; x1 += k0 + 2u;
  TFR(13) TFR(15) TFR(26) TFR(6)   x0 += k0;  x1 += k1 + 3u;
  TFR(17) TFR(29) TFR(16) TFR(24)  x0 += k1;  x1 += ks2 + 4u;
  TFR(13) TFR(15) TFR(26) TFR(6)   x0 += ks2; x1 += k0 + 5u;
#undef TFR
  o0 = x0; o1 = x1;
}

__device__ __forceinline__ float bits_to_normal(unsigned bits) {
  float f = __uint_as_float((bits >> 9) | 0x3f800000u) - 1.0f;  // [0,1)
  const float lo = -0.99999994f;                                 // nextafter(-1,0)
  float x = fmaxf(lo, fmaf(f, 2.0f, lo));
  float w = -log1pf(-x * x);
  float p;
  if (w < 5.0f) {
    w = w - 2.5f;
    p = 2.81022636e-08f;
    p = fmaf(p, w, 3.43273939e-07f);
    p = fmaf(p, w, -3.5233877e-06f);
    p = fmaf(p, w, -4.39150654e-06f);
    p = fmaf(p, w, 0.00021858087f);
    p = fmaf(p, w, -0.00125372503f);
    p = fmaf(p, w, -0.00417768164f);
    p = fmaf(p, w, 0.246640727f);
    p = fmaf(p, w, 1.50140941f);
  } else {
    w = sqrtf(w) - 3.0f;
    p = -0.000200214257f;
    p = fmaf(p, w, 0.000100950558f);
    p = fmaf(p, w, 0.00134934322f);
    p = fmaf(p, w, -0.00367342844f);
    p = fmaf(p, w, 0.00573950773f);
    p = fmaf(p, w, -0.0076224613f);
    p = fmaf(p, w, 0.00943887047f);
    p = fmaf(p, w, 1.00167406f);
    p = fmaf(p, w, 2.83297682f);
  }
  return 1.41421356237f * (p * x);
}

// ---------------- fused prep: rel_type scales + W->bf16 transpose ----------------
__global__ __launch_bounds__(256) void k_prep(
    const float* __restrict__ rtg, const float* __restrict__ rth,
    float* __restrict__ sg, float* __restrict__ sh,
    const float* __restrict__ W1, const float* __restrict__ W2,
    unsigned short* __restrict__ WtG) {
  int i = blockIdx.x * 256 + threadIdx.x;
  if (i < ROWS) {
    float4 r = ((const float4*)rtg)[i];
    sg[i] = (r.x + r.y + r.z + r.w) * 0.25f;
  }
  int j = i - ROWS;
  if (j >= 0 && j < HROWS) {
    float4 r = ((const float4*)rth)[j];
    sh[j] = (r.x + r.y + r.z + r.w) * 0.25f;
  }
  if (i < 32768) {
    int w = i >> 14, rem = i & 16383;
    int c = rem & 127, k = rem >> 7;
    const float* W = w ? W2 : W1;
    WtG[w * 16384 + c * 128 + k] = f2bf(W[k * 128 + c]);
  }
}

// ---------------- stats reduction: single block, 256 threads ----------------
__global__ __launch_bounds__(256) void k_red(const float* __restrict__ partials,
                                             float* __restrict__ stats) {
  int t = threadIdx.x;
  float s = 0.f;
#pragma unroll 5
  for (int r = 0; r < NBLK2; ++r) s += partials[(size_t)r * 256 + t];
  stats[t] = s;
}

// ---------------- edge MLP layer: 5-tile pipelined bf16 MFMA GEMM ----------------
// Each block: load W frags once, then loop 5 tiles of 64 rows:
//   write prefetched regs -> LDS (convert/BN) | issue next tile's global loads |
//   barrier | MFMA | epilogue (Y store + reg-stats accumulate)
// Stats: per-block partial store (no global atomics — R4/R5 lesson).
#define XPITCH 136
template <int MODE>
__global__ __launch_bounds__(256) void k_edge_gemm(
    const float* __restrict__ v, const unsigned short* __restrict__ WtG,
    const unsigned short* __restrict__ Yin, unsigned short* __restrict__ Yout,
    const float* __restrict__ bias,
    const float* __restrict__ gmm, const float* __restrict__ beta,
    const float* __restrict__ stats_in, float* __restrict__ partials) {
  __shared__ unsigned short Xt[64 * XPITCH];
  __shared__ float aColP[132], bColP[132];
  __shared__ float bsum[128], bssq[128];
  const int tid = threadIdx.x;
  const int lane = tid & 63, wid = tid >> 6;
  const int l15 = lane & 15, lq = lane >> 4;
  const int cb = wid * 32;
  const int rsi = tid >> 2, q = tid & 3, k0 = q * 32;

  if (tid < 128) {
    bsum[tid] = 0.f; bssq[tid] = 0.f;
    if (MODE == 1) {
      float s = stats_in[tid], ss = stats_in[128 + tid];
      float mu = s * (1.f / ROWS);
      float var = fmaxf(ss * (1.f / ROWS) - mu * mu, 0.f);
      float rs = 1.f / sqrtf(var + EPSF);
      float a = rs * gmm[tid];
      int pi = tid + (tid >> 5);
      aColP[pi] = a; bColP[pi] = beta[tid] - mu * a;
    }
  }

  // W fragments: global -> registers, once per block (L2-hot 32KB)
  const unsigned short* WA = WtG + (cb + l15) * 128 + lq * 8;
  bf16x8 a0[4], a1[4];
#pragma unroll
  for (int kc = 0; kc < 4; ++kc) {
    a0[kc] = *(const bf16x8*)(WA + kc * 32);
    a1[kc] = *(const bf16x8*)(WA + 16 * 128 + kc * 32);
  }
  // bias once per block
  float4 bi0 = *(const float4*)&bias[cb + lq * 4];
  float4 bi1 = *(const float4*)&bias[cb + 16 + lq * 4];
  f32x4 bv0 = {bi0.x, bi0.y, bi0.z, bi0.w};
  f32x4 bv1 = {bi1.x, bi1.y, bi1.z, bi1.w};
  // persistent per-thread stats accumulators (across tiles)
  f32x4 s0 = {0.f,0.f,0.f,0.f}, ss0 = {0.f,0.f,0.f,0.f};
  f32x4 s1 = {0.f,0.f,0.f,0.f}, ss1 = {0.f,0.f,0.f,0.f};

  // prefetch registers (single set; ds_write reads them at issue, so the next
  // tile's global_load may overwrite afterwards without extra waits)
  float4 ra[4], rb[4];   // MODE 0
  uint4  rw[4];          // MODE 1

  auto LOAD = [&](int tile) {
    if (MODE == 0) {
      int g = tile * 64 + rsi;
      int b = g / EE; int e = g - b * EE;
      int i = e / 99; int jj = e - i * 99; int j = jj + ((jj >= i) ? 1 : 0);
      int vsrc = (q < 2) ? ((b * NN + i) * FF + q * 32)
                         : ((b * NN + j) * FF + (q - 2) * 32);
#pragma unroll
      for (int i2 = 0; i2 < 4; ++i2) {
        ra[i2] = *(const float4*)&v[vsrc + i2 * 8];
        rb[i2] = *(const float4*)&v[vsrc + i2 * 8 + 4];
      }
    } else {
      const unsigned short* src = Yin + (size_t)(tile * 64 + rsi) * 128 + k0;
#pragma unroll
      for (int i2 = 0; i2 < 4; ++i2) rw[i2] = *(const uint4*)&src[i2 * 8];
    }
  };
  auto WRITE = [&]() {
    if (MODE == 0) {
#pragma unroll
      for (int i2 = 0; i2 < 4; ++i2) {
        uint4 pk;
        pk.x = pk2(ra[i2].x, ra[i2].y); pk.y = pk2(ra[i2].z, ra[i2].w);
        pk.z = pk2(rb[i2].x, rb[i2].y); pk.w = pk2(rb[i2].z, rb[i2].w);
        *(uint4*)&Xt[rsi * XPITCH + k0 + i2 * 8] = pk;
      }
    } else {
#pragma unroll
      for (int i2 = 0; i2 < 4; ++i2) {
        unsigned rr[4] = {rw[i2].x, rw[i2].y, rw[i2].z, rw[i2].w};
        unsigned ow[4];
#pragma unroll
        for (int u = 0; u < 4; ++u) {
          int k = k0 + i2 * 8 + u * 2;
          int p1 = k + (k >> 5);
          float xl = __uint_as_float(rr[u] << 16);
          float xh = __uint_as_float(rr[u] & 0xffff0000u);
          xl = lrelu(fmaf(xl, aColP[p1], bColP[p1]));
          xh = lrelu(fmaf(xh, aColP[p1 + 1], bColP[p1 + 1]));
          ow[u] = pk2(xl, xh);
        }
        uint4 pk; pk.x = ow[0]; pk.y = ow[1]; pk.z = ow[2]; pk.w = ow[3];
        *(uint4*)&Xt[rsi * XPITCH + k0 + i2 * 8] = pk;
      }
    }
  };

  if (MODE == 1) __syncthreads();   // aColP/bColP visible before first WRITE

  const int tile0 = blockIdx.x * TPB;
  LOAD(tile0);
  for (int tt = 0; tt < TPB; ++tt) {
    if (tt) __syncthreads();        // previous tile's MFMA reads of Xt complete
    WRITE();                        // regs -> LDS (waits vmcnt internally)
    if (tt + 1 < TPB) LOAD(tile0 + tt + 1);   // prefetch overlaps MFMA+epilogue
    __syncthreads();                // Xt ready

    f32x4 acc[2][4];
#pragma unroll
    for (int a = 0; a < 2; ++a)
#pragma unroll
      for (int b2 = 0; b2 < 4; ++b2) acc[a][b2] = (f32x4){0.f, 0.f, 0.f, 0.f};
    const unsigned short* Bb = &Xt[l15 * XPITCH + lq * 8];
#pragma unroll
    for (int kc = 0; kc < 4; ++kc) {
      int ko = kc * 32;
#pragma unroll
      for (int rbi = 0; rbi < 4; ++rbi) {
        bf16x8 bfr = *(const bf16x8*)(Bb + rbi * 16 * XPITCH + ko);
        acc[0][rbi] = __builtin_amdgcn_mfma_f32_16x16x32_bf16(a0[kc], bfr, acc[0][rbi], 0, 0, 0);
        acc[1][rbi] = __builtin_amdgcn_mfma_f32_16x16x32_bf16(a1[kc], bfr, acc[1][rbi], 0, 0, 0);
      }
    }

    int r0 = (tile0 + tt) * 64;
#pragma unroll
    for (int rbi = 0; rbi < 4; ++rbi) {
      size_t r = (size_t)(r0 + rbi * 16 + l15);
      f32x4 y0 = acc[0][rbi] + bv0;
      f32x4 y1 = acc[1][rbi] + bv1;
      uint2 w0; w0.x = pk2(y0.x, y0.y); w0.y = pk2(y0.z, y0.w);
      uint2 w1; w1.x = pk2(y1.x, y1.y); w1.y = pk2(y1.z, y1.w);
      *(uint2*)&Yout[r * 128 + cb + lq * 4] = w0;
      *(uint2*)&Yout[r * 128 + cb + 16 + lq * 4] = w1;
      s0 += y0; ss0 += y0 * y0;
      s1 += y1; ss1 += y1 * y1;
    }
  }

  // LDS reduce (bank-parallel), contiguous per-block partial store
#pragma unroll
  for (int u = 0; u < 4; ++u) {
    atomicAdd(&bsum[cb + lq * 4 + u], s0[u]);
    atomicAdd(&bssq[cb + lq * 4 + u], ss0[u]);
    atomicAdd(&bsum[cb + 16 + lq * 4 + u], s1[u]);
    atomicAdd(&bssq[cb + 16 + lq * 4 + u], ss1[u]);
  }
  __syncthreads();
  if (tid < 128) {
    partials[(size_t)blockIdx.x * 256 + tid] = bsum[tid];
    partials[(size_t)blockIdx.x * 256 + 128 + tid] = bssq[tid];
  }
}

// ---------------- receiver gather-reduce: hidden_g ----------------
__global__ __launch_bounds__(128) void k_recv(
    const unsigned short* __restrict__ Y, const float* __restrict__ stats2,
    const float* __restrict__ g2, const float* __restrict__ be2,
    const float* __restrict__ scaleg, const float* __restrict__ v,
    float* __restrict__ hg) {
  int bn = blockIdx.x; int b = bn / NN, n = bn - b * NN;
  int h = threadIdx.x;
  float s = stats2[h], ss = stats2[128 + h];
  float mu = s * (1.f / ROWS);
  float var = fmaxf(ss * (1.f / ROWS) - mu * mu, 0.f);
  float rs = 1.f / sqrtf(var + EPSF);
  float a = rs * g2[h]; float bc = be2[h] - mu * a;
  float sv = (h >= 64) ? v[(b * NN + n) * FF + (h - 64)] : 0.f;
  float acc = 0.f;
#pragma unroll 4
  for (int i = 0; i < NN; ++i) {
    if (i == n) continue;
    int e = i * 99 + ((n < i) ? n : n - 1);
    int row = b * EE + e;
    float y = bf2f(Y[(size_t)row * 128 + h]);
    float msgv = lrelu(y * a + bc);
    float pre = (h < 64) ? v[(b * NN + i) * FF + h] : sv;
    float ag = lrelu(fmaf(msgv, scaleg[row], pre));
    acc += ag;
  }
  hg[bn * 128 + h] = acc * 0.5f;  // / D
}

// ---------------- hyper path ----------------
__global__ __launch_bounds__(128) void k_h1(const float* __restrict__ I_HG,
                                            const float* __restrict__ v,
                                            const float* __restrict__ W1h,
                                            const float* __restrict__ b1h,
                                            float* __restrict__ y1h) {
  int bm = blockIdx.x; int b = bm / MM, m = bm - b * MM;
  __shared__ float prerow[FF];
  int t = threadIdx.x;
  if (t < FF) {
    float s = 0.f;
    for (int n = 0; n < NN; ++n)
      s = fmaf(I_HG[(b * NN + n) * MM + m], v[(b * NN + n) * FF + t], s);
    prerow[t] = s;
  }
  __syncthreads();
  float y = b1h[t];
  for (int f = 0; f < FF; ++f) y = fmaf(prerow[f], W1h[f * 128 + t], y);
  y1h[bm * 128 + t] = y;
}

__global__ __launch_bounds__(64) void k_colstats(const float* __restrict__ X, int R,
                                                 float* __restrict__ stats) {
  int c = blockIdx.x;
  int t = threadIdx.x;
  float s = 0.f, ss = 0.f;
  for (int r = t; r < R; r += 64) {
    float x = X[(size_t)r * 128 + c];
    s += x; ss += x * x;
  }
  for (int off = 32; off; off >>= 1) {
    s += __shfl_down(s, off, 64);
    ss += __shfl_down(ss, off, 64);
  }
  if (t == 0) { stats[c] = s; stats[128 + c] = ss; }
}

__global__ __launch_bounds__(128) void k_h2(const float* __restrict__ y1h,
                                            const float* __restrict__ statsh1,
                                            const float* __restrict__ g1h,
                                            const float* __restrict__ be1h,
                                            const float* __restrict__ W2h,
                                            const float* __restrict__ b2h,
                                            float* __restrict__ y2h) {
  int bm = blockIdx.x; int t = threadIdx.x;
  __shared__ float trow[128];
  float s = statsh1[t], ss = statsh1[128 + t];
  float mu = s * (1.f / HROWS);
  float var = fmaxf(ss * (1.f / HROWS) - mu * mu, 0.f);
  float rs = 1.f / sqrtf(var + EPSF);
  float a = rs * g1h[t]; float bc = be1h[t] - mu * a;
  trow[t] = lrelu(y1h[bm * 128 + t] * a + bc);
  __syncthreads();
  float y = b2h[t];
  for (int f = 0; f < 128; ++f) y = fmaf(trow[f], W2h[f * 128 + t], y);
  y2h[bm * 128 + t] = y;
}

__global__ __launch_bounds__(128) void k_h3(const float* __restrict__ y2h,
                                            const float* __restrict__ statsh2,
                                            const float* __restrict__ g2h,
                                            const float* __restrict__ be2h,
                                            const float* __restrict__ scaleh,
                                            const float* __restrict__ I_HG,
                                            float* __restrict__ hh) {
  int bn = blockIdx.x; int b = bn / NN, n = bn - b * NN;
  int h = threadIdx.x;
  float s = statsh2[h], ss = statsh2[128 + h];
  float mu = s * (1.f / HROWS);
  float var = fmaxf(ss * (1.f / HROWS) - mu * mu, 0.f);
  float rs = 1.f / sqrtf(var + EPSF);
  float a = rs * g2h[h]; float bc = be2h[h] - mu * a;
  float acc = 0.f;
  for (int m = 0; m < MM; ++m) {
    float x = lrelu(y2h[(b * MM + m) * 128 + h] * a + bc);
    acc = fmaf(x * scaleh[b * MM + m], I_HG[(b * NN + n) * MM + m], acc);
  }
  hh[bn * 128 + h] = acc * 0.5f;  // / D
}

// ---------------- v layer + heads ----------------
__global__ __launch_bounds__(128) void k_ve(
    const float* __restrict__ hg, const float* __restrict__ hh,
    const float* __restrict__ Wo1, const float* __restrict__ bo1,
    const float* __restrict__ Wa, const float* __restrict__ ba,
    const float* __restrict__ Wm, const float* __restrict__ bm,
    float* __restrict__ valpha, float* __restrict__ vmu, float* __restrict__ vcore) {
  __shared__ __align__(16) float cat[8][256];
  __shared__ float vres[8][128];
  __shared__ float lgs[KK], mrow[KK * DD], alsh[KK];
  int r0 = blockIdx.x * 8;
  int t = threadIdx.x;
  for (int q = t; q < 2048; q += 128) {
    int rr = q >> 8, k = q & 255;
    cat[rr][k] = (k < 128) ? hg[(r0 + rr) * 128 + k] : hh[(r0 + rr) * 128 + (k - 128)];
  }
  __syncthreads();
  float acc[8] = {0, 0, 0, 0, 0, 0, 0, 0};
  for (int k = 0; k < 256; ++k) {
    float wv = Wo1[k * 128 + t];
#pragma unroll
    for (int q = 0; q < 8; ++q) acc[q] = fmaf(cat[q][k], wv, acc[q]);
  }
  float bb = bo1[t];
#pragma unroll
  for (int q = 0; q < 8; ++q) vres[q][t] = lrelu(acc[q] + bb);
  __syncthreads();
  for (int q = 0; q < 8; ++q) {
    int row = r0 + q;
    if (t < KK) {
      float s = ba[t];
      for (int f = 0; f < 128; ++f) s = fmaf(vres[q][f], Wa[f * KK + t], s);
      lgs[t] = s;
    } else if (t >= 64 && t < 64 + KK * DD) {
      int c = t - 64;
      float s = bm[c];
      for (int f = 0; f < 128; ++f) s = fmaf(vres[q][f], Wm[f * (KK * DD) + c], s);
      mrow[c] = s;
      vmu[row * (KK * DD) + c] = s;
    }
    __syncthreads();
    if (t < KK) {
      float mx = lgs[0];
      for (int k2 = 1; k2 < KK; ++k2) mx = fmaxf(mx, lgs[k2]);
      float se = 0.f;
      for (int k2 = 0; k2 < KK; ++k2) se += expf(lgs[k2] - mx);
      float al = expf(lgs[t] - mx) / se;
      alsh[t] = al;
      valpha[row * KK + t] = al;
    }
    __syncthreads();
    if (t < DD) {
      float s = 0.f;
      for (int k2 = 0; k2 < KK; ++k2) s = fmaf(alsh[k2], mrow[k2 * DD + t], s);
      vcore[row * DD + t] = s;
    }
    __syncthreads();
  }
}

// ---------------- decoder outputs (exact JAX threefry noise, partitionable XOR) -------
__global__ __launch_bounds__(64) void k_out(const float* __restrict__ data,
                                            const float* __restrict__ valpha,
                                            const float* __restrict__ vmu,
                                            const float* __restrict__ vcore,
                                            float* __restrict__ out) {
  int bn = blockIdx.x; int t = threadIdx.x;
  __shared__ float nz[8][2];
  __shared__ float insarr[8][2];
  __shared__ float alsh[KK];
  if (t < 16) {
    int s = t >> 1, d = t & 1;
    unsigned fk0, fk1;
    tf2x32(0u, 1234u, 0u, (unsigned)s, fk0, fk1);        // fold_in(key(1234), s)
    unsigned flat = (unsigned)(bn * 2 + d);
    unsigned o0, o1;
    tf2x32(fk0, fk1, 0u, flat, o0, o1);                   // counter-mode
    nz[s][d] = bits_to_normal(o0 ^ o1);                   // XOR both lanes
  }
  if (t < KK) alsh[t] = valpha[bn * KK + t];
  __syncthreads();
  if (t < 2) {
    int d = t;
    float ins0 = data[bn * 16 + d];
    float core = vcore[bn * 2 + d];
    float p = ins0;
    for (int s = 0; s < 8; ++s) {
      insarr[s][d] = p;
      p = (p + core) + nz[s][d];
      out[(bn * 8 + s) * 2 + d] = p;
    }
  }
  __syncthreads();
  for (int q = t; q < 160; q += 64) {
    int k = q % KK;
    out[25600 + bn * 160 + q] = alsh[k];
  }
  for (int q = t; q < 320; q += 64) {
    int s = q / 40, kd = q - s * 40, d = kd & 1;
    out[281600 + bn * 320 + q] = vmu[bn * 40 + kd] + insarr[s][d];
  }
  for (int q = t; q < 320; q += 64) out[793600 + bn * 320 + q] = 1.0f;
}

extern "C" void kernel_launch(void* const* d_in, const int* in_sizes, int n_in,
                              void* d_out, int out_size, void* d_ws, size_t ws_size,
                              hipStream_t stream) {
  const float* data  = (const float*)d_in[0];
  const float* rtg   = (const float*)d_in[3];
  const float* rth   = (const float*)d_in[4];
  const float* I_HG  = (const float*)d_in[5];
  const float* v     = (const float*)d_in[6];
  const float* W1g   = (const float*)d_in[7];
  const float* b1g   = (const float*)d_in[8];
  const float* g1g   = (const float*)d_in[9];
  const float* be1g  = (const float*)d_in[10];
  const float* W2g   = (const float*)d_in[11];
  const float* b2g   = (const float*)d_in[12];
  const float* g2g   = (const float*)d_in[13];
  const float* be2g  = (const float*)d_in[14];
  const float* W1h   = (const float*)d_in[15];
  const float* b1h   = (const float*)d_in[16];
  const float* g1h   = (const float*)d_in[17];
  const float* be1h  = (const float*)d_in[18];
  const float* W2h   = (const float*)d_in[19];
  const float* b2h   = (const float*)d_in[20];
  const float* g2h   = (const float*)d_in[21];
  const float* be2h  = (const float*)d_in[22];
  const float* Wo1   = (const float*)d_in[23];
  const float* bo1   = (const float*)d_in[24];
  const float* Wa    = (const float*)d_in[25];
  const float* ba    = (const float*)d_in[26];
  const float* Wm    = (const float*)d_in[27];
  const float* bm    = (const float*)d_in[28];
  char* wsb  = (char*)d_ws;
  float* out = (float*)d_out;

  // byte-offset workspace layout
  unsigned short* Ybf = (unsigned short*)wsb;                        // 40,550,400 B
  float* stats1  = (float*)(wsb + 40550400);                         // 256
  float* stats2  = stats1 + 256;
  float* statsh1 = stats2 + 256;
  float* statsh2 = statsh1 + 256;
  float* scaleg  = (float*)(wsb + 40550400 + 4096);                  // ROWS
  float* scaleh  = scaleg + ROWS;                                     // HROWS
  float* hg      = scaleh + HROWS;                                    // 1600*128
  float* hh      = hg + BN_CNT * 128;
  float* y1h     = hh + BN_CNT * 128;                                 // 800*128
  float* y2h     = y1h + HROWS * 128;
  float* va      = y2h + HROWS * 128;                                 // 1600*20
  float* vmu     = va + BN_CNT * KK;                                  // 1600*40
  float* vcore   = vmu + BN_CNT * KK * DD;                            // 1600*2
  unsigned short* WtG = (unsigned short*)(vcore + BN_CNT * DD);       // 2*16384 bf16
  float* partials = (float*)(WtG + 2 * 16384);                        // 495*256 f32

  k_prep<<<(ROWS + HROWS + 255) / 256, 256, 0, stream>>>(rtg, rth, scaleg, scaleh,
                                                         W1g, W2g, WtG);
  k_edge_gemm<0><<<NBLK2, 256, 0, stream>>>(v, WtG, nullptr, Ybf, b1g,
                                            nullptr, nullptr, nullptr, partials);
  k_red<<<1, 256, 0, stream>>>(partials, stats1);
  k_edge_gemm<1><<<NBLK2, 256, 0, stream>>>(v, WtG + 16384, Ybf, Ybf, b2g,
                                            g1g, be1g, stats1, partials);
  k_red<<<1, 256, 0, stream>>>(partials, stats2);
  k_recv<<<BN_CNT, 128, 0, stream>>>(Ybf, stats2, g2g, be2g, scaleg, v, hg);
  k_h1<<<HROWS, 128, 0, stream>>>(I_HG, v, W1h, b1h, y1h);
  k_colstats<<<128, 64, 0, stream>>>(y1h, HROWS, statsh1);
  k_h2<<<HROWS, 128, 0, stream>>>(y1h, statsh1, g1h, be1h, W2h, b2h, y2h);
  k_colstats<<<128, 64, 0, stream>>>(y2h, HROWS, statsh2);
  k_h3<<<BN_CNT, 128, 0, stream>>>(y2h, statsh2, g2h, be2h, scaleh, I_HG, hh);
  k_ve<<<BN_CNT / 8, 128, 0, stream>>>(hg, hh, Wo1, bo1, Wa, ba, Wm, bm, va, vmu, vcore);
  k_out<<<BN_CNT, 64, 0, stream>>>(data, va, vmu, vcore, out);
}